// Round 5
// baseline (1180.517 us; speedup 1.0000x reference)
//
#include <hip/hip_runtime.h>

// GraphSAGE 3-layer + BN(train stats) + ReLU + classifier, MI355X.
// R5: GEMM restructured m97-style: K-concat dual source (one staging pass),
//     BM=128/BK=64 (64 MFMA per wave per barrier), global_load_lds width-16
//     staging for A and B. BN+ReLU materialized in-place (bn_apply) so GEMM
//     A-streams are plain bf16 (DMA-stageable). CSR build (R4) unchanged.

#define DEV static __device__ __forceinline__

typedef unsigned short us;
typedef __attribute__((ext_vector_type(8))) __bf16 bf16x8;
typedef __attribute__((ext_vector_type(4))) float f32x4;

DEV float bf2f(us u) { return __uint_as_float(((unsigned)u) << 16); }
DEV us f2bf(float f) {
    unsigned u = __float_as_uint(f);
    unsigned r = u + 0x7fffu + ((u >> 16) & 1u);  // round-nearest-even
    return (us)(r >> 16);
}

typedef __attribute__((address_space(3))) void lds_void;
typedef const __attribute__((address_space(1))) void gbl_void;
DEV void gll16(const void* g, void* l) {
    // stages 64 lanes x 16B -> LDS at (wave-uniform base) + lane*16
    __builtin_amdgcn_global_load_lds((gbl_void*)g, (lds_void*)l, 16, 0, 0);
}

// ---------------- CSR build (bucketed two-level, R4) ----------------

__global__ void detect_i64(const int* ei, int* flag) {
    int z = (ei[1] == 0) & (ei[3] == 0) & (ei[5] == 0) & (ei[7] == 0);
    *flag = z;
}

__global__ void bucket_hist(const int* __restrict__ ei, const int* __restrict__ flag,
                            int E, int* __restrict__ hist2, int NB, int chunk) {
    __shared__ int h[256];
    const int g = blockIdx.x, t = threadIdx.x;
    const bool i64 = (*flag != 0);
    h[t] = 0;
    __syncthreads();
    int beg = g * chunk, end = min(beg + chunk, E);
    for (int e = beg + t; e < end; e += 256) {
        int d = i64 ? ei[2 * (E + e)] : ei[E + e];
        atomicAdd(&h[d >> 9], 1);
    }
    __syncthreads();
    if (t < NB) hist2[g * NB + t] = h[t];
}

__global__ void bucket_offsets(int* __restrict__ hist2, int* __restrict__ bucketBase,
                               int* __restrict__ rp, int N, int G, int NB) {
    __shared__ int tot[256];
    const int t = threadIdx.x;
    int sum = 0;
    if (t < NB)
        for (int g = 0; g < G; ++g) sum += hist2[g * NB + t];
    tot[t] = sum;
    __syncthreads();
    for (int off = 1; off < 256; off <<= 1) {
        int v = (t >= off) ? tot[t - off] : 0;
        __syncthreads();
        tot[t] += v;
        __syncthreads();
    }
    int base = tot[t] - sum;
    if (t < NB) {
        bucketBase[t] = base;
        int run = base;
        for (int g = 0; g < G; ++g) {
            int v = hist2[g * NB + t];
            hist2[g * NB + t] = run;
            run += v;
        }
        if (t == NB - 1) {
            bucketBase[NB] = tot[t];
            rp[N] = tot[t];
        }
    }
}

__global__ void scatter8(const int* __restrict__ ei, const int* __restrict__ flag,
                         int E, const int* __restrict__ hist2, uint2* __restrict__ ebuf,
                         int NB, int chunk) {
    __shared__ int off[256];
    const int g = blockIdx.x, t = threadIdx.x;
    const bool i64 = (*flag != 0);
    if (t < NB) off[t] = hist2[g * NB + t];
    __syncthreads();
    int beg = g * chunk, end = min(beg + chunk, E);
    for (int e = beg + t; e < end; e += 256) {
        int s = i64 ? ei[2 * e] : ei[e];
        int d = i64 ? ei[2 * (E + e)] : ei[E + e];
        int p = atomicAdd(&off[d >> 9], 1);
        ebuf[p] = make_uint2((unsigned)s, (unsigned)d);
    }
}

__global__ void fine_csr(const uint2* __restrict__ ebuf, const int* __restrict__ bucketBase,
                         int N, int* __restrict__ rp, int* __restrict__ csr) {
    __shared__ int cnt[512];
    __shared__ int red[256];
    const int b = blockIdx.x, t = threadIdx.x;
    const int node0 = b << 9;
    cnt[t] = 0;
    cnt[t + 256] = 0;
    __syncthreads();
    const int ebeg = bucketBase[b], eend = bucketBase[b + 1];
    for (int e = ebeg + t; e < eend; e += 256) {
        uint2 r = ebuf[e];
        atomicAdd(&cnt[r.y & 511], 1);
    }
    __syncthreads();
    int c0 = cnt[2 * t], c1 = cnt[2 * t + 1];
    int s = c0 + c1;
    red[t] = s;
    __syncthreads();
    for (int off = 1; off < 256; off <<= 1) {
        int v = (t >= off) ? red[t - off] : 0;
        __syncthreads();
        red[t] += v;
        __syncthreads();
    }
    int pre = red[t] - s;
    int n0 = node0 + 2 * t;
    if (n0 < N) rp[n0] = ebeg + pre;
    if (n0 + 1 < N) rp[n0 + 1] = ebeg + pre + c0;
    __syncthreads();
    cnt[2 * t] = ebeg + pre;
    cnt[2 * t + 1] = ebeg + pre + c0;
    __syncthreads();
    for (int e = ebeg + t; e < eend; e += 256) {
        uint2 r = ebuf[e];
        int p = atomicAdd(&cnt[r.y & 511], 1);
        csr[p] = (int)r.x;
    }
}

// ---------------- dtype convert / weight concat ----------------

__global__ void f32_to_bf16_kernel(const float* __restrict__ x, us* __restrict__ o, int n4) {
    for (int i = blockIdx.x * blockDim.x + threadIdx.x; i < n4; i += gridDim.x * blockDim.x) {
        float4 v = ((const float4*)x)[i];
        ushort4 r;
        r.x = f2bf(v.x); r.y = f2bf(v.y); r.z = f2bf(v.z); r.w = f2bf(v.w);
        ((ushort4*)o)[i] = r;
    }
}

struct WSeg { const float* s; us* d; int n4; int l2w4; int stride; };
struct WConvAll { WSeg seg[7]; };

// copy f32 [rows][w] -> bf16 at d + row*stride (+col), w4 = w/4 = 1<<l2w4
__global__ void conv_weights(WConvAll wc) {
    for (int sg = 0; sg < 7; ++sg) {
        WSeg w = wc.seg[sg];
        for (int i = blockIdx.x * blockDim.x + threadIdx.x; i < w.n4; i += gridDim.x * blockDim.x) {
            float4 v = ((const float4*)w.s)[i];
            ushort4 r;
            r.x = f2bf(v.x); r.y = f2bf(v.y); r.z = f2bf(v.z); r.w = f2bf(v.w);
            int row = i >> w.l2w4;
            int col = (i - (row << w.l2w4)) * 4;
            *(ushort4*)(w.d + (size_t)row * w.stride + col) = r;
        }
    }
}

// ---------------- mean aggregation (wave per node) ----------------

template <int VEC>  // cols = 64*VEC
__global__ void agg_mean(const us* __restrict__ X, const int* __restrict__ rp,
                         const int* __restrict__ csr, us* __restrict__ M, int n) {
    const int cols = VEC * 64;
    int w = blockIdx.x * (blockDim.x >> 6) + (threadIdx.x >> 6);
    int lane = threadIdx.x & 63;
    if (w >= n) return;
    int beg = rp[w], end = rp[w + 1];
    float acc[VEC];
#pragma unroll
    for (int i = 0; i < VEC; ++i) acc[i] = 0.f;
    int e = beg;
    for (; e + 2 <= end; e += 2) {
        int j0 = csr[e], j1 = csr[e + 1];
        if (VEC == 2) {
            unsigned u0 = *(const unsigned*)(X + (size_t)j0 * cols + lane * 2);
            unsigned u1 = *(const unsigned*)(X + (size_t)j1 * cols + lane * 2);
            acc[0] += __uint_as_float(u0 << 16) + __uint_as_float(u1 << 16);
            acc[1] += __uint_as_float(u0 & 0xffff0000u) + __uint_as_float(u1 & 0xffff0000u);
        } else {
            uint2 u0 = *(const uint2*)(X + (size_t)j0 * cols + lane * 4);
            uint2 u1 = *(const uint2*)(X + (size_t)j1 * cols + lane * 4);
            acc[0] += __uint_as_float(u0.x << 16) + __uint_as_float(u1.x << 16);
            acc[1] += __uint_as_float(u0.x & 0xffff0000u) + __uint_as_float(u1.x & 0xffff0000u);
            acc[2] += __uint_as_float(u0.y << 16) + __uint_as_float(u1.y << 16);
            acc[3] += __uint_as_float(u0.y & 0xffff0000u) + __uint_as_float(u1.y & 0xffff0000u);
        }
    }
    if (e < end) {
        int j0 = csr[e];
        if (VEC == 2) {
            unsigned u0 = *(const unsigned*)(X + (size_t)j0 * cols + lane * 2);
            acc[0] += __uint_as_float(u0 << 16);
            acc[1] += __uint_as_float(u0 & 0xffff0000u);
        } else {
            uint2 u0 = *(const uint2*)(X + (size_t)j0 * cols + lane * 4);
            acc[0] += __uint_as_float(u0.x << 16);
            acc[1] += __uint_as_float(u0.x & 0xffff0000u);
            acc[2] += __uint_as_float(u0.y << 16);
            acc[3] += __uint_as_float(u0.y & 0xffff0000u);
        }
    }
    float inv = 1.0f / (float)max(end - beg, 1);
    us* q = M + (size_t)w * cols + lane * VEC;
    if (VEC == 2) {
        *(ushort2*)q = make_ushort2(f2bf(acc[0] * inv), f2bf(acc[1] * inv));
    } else {
        *(ushort4*)q = make_ushort4(f2bf(acc[0] * inv), f2bf(acc[1] * inv),
                                    f2bf(acc[2] * inv), f2bf(acc[3] * inv));
    }
}

// layer-3 post-GEMM aggregation: H[i][c] = mean_j Yc[j][c] + Yc[i][128+c] + bias[c]
__global__ void agg_post(const us* __restrict__ Yc, const int* __restrict__ rp,
                         const int* __restrict__ csr, const float* __restrict__ bias,
                         us* __restrict__ H, int n) {
    int w = blockIdx.x * (blockDim.x >> 6) + (threadIdx.x >> 6);
    int lane = threadIdx.x & 63;
    if (w >= n) return;
    int beg = rp[w], end = rp[w + 1];
    float a0 = 0.f, a1 = 0.f;
    int e = beg;
    for (; e + 2 <= end; e += 2) {
        int j0 = csr[e], j1 = csr[e + 1];
        unsigned u0 = *(const unsigned*)(Yc + (size_t)j0 * 256 + lane * 2);
        unsigned u1 = *(const unsigned*)(Yc + (size_t)j1 * 256 + lane * 2);
        a0 += __uint_as_float(u0 << 16) + __uint_as_float(u1 << 16);
        a1 += __uint_as_float(u0 & 0xffff0000u) + __uint_as_float(u1 & 0xffff0000u);
    }
    if (e < end) {
        unsigned u0 = *(const unsigned*)(Yc + (size_t)csr[e] * 256 + lane * 2);
        a0 += __uint_as_float(u0 << 16);
        a1 += __uint_as_float(u0 & 0xffff0000u);
    }
    float inv = 1.0f / (float)max(end - beg, 1);
    unsigned uz = *(const unsigned*)(Yc + (size_t)w * 256 + 128 + lane * 2);
    float2 bv = *(const float2*)(bias + lane * 2);
    float r0 = a0 * inv + __uint_as_float(uz << 16) + bv.x;
    float r1 = a1 * inv + __uint_as_float(uz & 0xffff0000u) + bv.y;
    *(ushort2*)(H + (size_t)w * 128 + lane * 2) = make_ushort2(f2bf(r0), f2bf(r1));
}

// ---------------- MFMA GEMM, K-concat dual source, global_load_lds staging ----
// C = [A0|A1] @ Wcat^T + bias. A0:[n,K0], A1:[n,K1] bf16; Wcat:[outc,K0+K1] bf16.
// BK=64. LDS fragment layout: 1KB block per (tile, kchunk): base + lane*16.

template <int BM, int BN, int WM, int WN>
__launch_bounds__(256)
__global__ void gemm_mfma(const us* __restrict__ A0, int K0,
                          const us* __restrict__ A1, int K1,
                          const us* __restrict__ W, const float* __restrict__ bias,
                          int n, int outc, us* __restrict__ Cbf, float* __restrict__ Cf) {
    constexpr int MT = WM / 16;
    constexpr int NT = WN / 16;
    constexpr int WCols = BN / WN;
    constexpr int ACH = BM * 8;  // 16B chunks per A tile (BM x 64 bf16)
    constexpr int BCH = BN * 8;
    __shared__ __align__(16) us As[BM * 64];
    __shared__ __align__(16) us Bs[BN * 64];

    const int t = threadIdx.x;
    const int wid = t >> 6, lane = t & 63;
    const int wr = wid / WCols, wcc = wid % WCols;
    const int row0 = blockIdx.x * BM;
    const int Kp = K0 + K1;
    const int l15 = lane & 15, l4 = lane >> 4;

    f32x4 acc[MT][NT];
#pragma unroll
    for (int i = 0; i < MT; ++i)
#pragma unroll
        for (int j = 0; j < NT; ++j) acc[i][j] = (f32x4){0.f, 0.f, 0.f, 0.f};

    for (int kc = 0; kc < Kp; kc += 64) {
        const us* A = (kc < K0) ? A0 : A1;
        const int rs = (kc < K0) ? K0 : K1;
        const int ko = (kc < K0) ? kc : kc - K0;
        // stage A: chunk blk=c>>6 -> LDS 1KB block blk; row=row0+(blk>>1)*16+(lane&15),
        // k = ko + (blk&1)*32 + (lane>>4)*8. (no row clamp: OOB reads land in ws pad)
#pragma unroll
        for (int c = t; c < ACH; c += 256) {
            int blk = c >> 6;
            int row = row0 + ((blk >> 1) << 4) + l15;
            int k = ko + ((blk & 1) << 5) + (l4 << 3);
            gll16(A + (size_t)row * rs + k, (char*)As + blk * 1024 + lane * 16);
        }
#pragma unroll
        for (int c = t; c < BCH; c += 256) {
            int blk = c >> 6;
            int col = ((blk >> 1) << 4) + l15;
            int k = kc + ((blk & 1) << 5) + (l4 << 3);
            gll16(W + (size_t)col * Kp + k, (char*)Bs + blk * 1024 + lane * 16);
        }
        __syncthreads();
#pragma unroll
        for (int kk2 = 0; kk2 < 2; ++kk2) {
            bf16x8 af[MT], bfr[NT];
#pragma unroll
            for (int mt = 0; mt < MT; ++mt)
                af[mt] = *(const bf16x8*)((char*)As + (((wr * MT + mt) << 1) + kk2) * 1024 + lane * 16);
#pragma unroll
            for (int nt = 0; nt < NT; ++nt)
                bfr[nt] = *(const bf16x8*)((char*)Bs + (((wcc * NT + nt) << 1) + kk2) * 1024 + lane * 16);
#pragma unroll
            for (int mt = 0; mt < MT; ++mt)
#pragma unroll
                for (int nt = 0; nt < NT; ++nt)
                    acc[mt][nt] = __builtin_amdgcn_mfma_f32_16x16x32_bf16(af[mt], bfr[nt], acc[mt][nt], 0, 0, 0);
        }
        __syncthreads();
    }

    // epilogue: C/D map col=lane&15, row=(lane>>4)*4+reg
#pragma unroll
    for (int mt = 0; mt < MT; ++mt) {
#pragma unroll
        for (int nt = 0; nt < NT; ++nt) {
            int col = wcc * WN + nt * 16 + l15;
            int rbase = row0 + wr * WM + mt * 16 + (l4 << 2);
            bool cok = col < outc;
            float bv = (bias != nullptr && cok) ? bias[col] : 0.f;
#pragma unroll
            for (int i = 0; i < 4; ++i) {
                int r = rbase + i;
                if (r < n && cok) {
                    float v = acc[mt][nt][i] + bv;
                    if (Cf) Cf[(size_t)r * outc + col] = v;
                    else Cbf[(size_t)r * outc + col] = f2bf(v);
                }
            }
        }
    }
}

// ---------------- BatchNorm ----------------

__global__ void bn_stats(const us* __restrict__ H, int n, int c,
                         float* __restrict__ s0, float* __restrict__ s1) {
    int col = threadIdx.x;
    if (col >= c) return;
    float s = 0.f, q = 0.f;
    for (int r = blockIdx.x; r < n; r += gridDim.x) {
        float v = bf2f(H[(size_t)r * c + col]);
        s += v;
        q += v * v;
    }
    atomicAdd(&s0[col], s);
    atomicAdd(&s1[col], q);
}

__global__ void bn_finalize(const float* __restrict__ s0, const float* __restrict__ s1,
                            const float* __restrict__ g, const float* __restrict__ be,
                            float fn, int c, float* __restrict__ scale, float* __restrict__ shift) {
    int col = threadIdx.x;
    if (col >= c) return;
    float mean = s0[col] / fn;
    float var = s1[col] / fn - mean * mean;
    float sc = g[col] * rsqrtf(var + 1e-5f);
    scale[col] = sc;
    shift[col] = be[col] - mean * sc;
}

__global__ void bn_apply(us* __restrict__ H, int n8, int c,
                         const float* __restrict__ scale, const float* __restrict__ shift) {
    int cdiv8 = c >> 3;
    for (int i = blockIdx.x * blockDim.x + threadIdx.x; i < n8; i += gridDim.x * blockDim.x) {
        int col = (i % cdiv8) << 3;
        uint4 v = ((const uint4*)H)[i];
        float f[8];
        f[0] = __uint_as_float(v.x << 16); f[1] = __uint_as_float(v.x & 0xffff0000u);
        f[2] = __uint_as_float(v.y << 16); f[3] = __uint_as_float(v.y & 0xffff0000u);
        f[4] = __uint_as_float(v.z << 16); f[5] = __uint_as_float(v.z & 0xffff0000u);
        f[6] = __uint_as_float(v.w << 16); f[7] = __uint_as_float(v.w & 0xffff0000u);
        float4 sc0 = *(const float4*)&scale[col];
        float4 sc1 = *(const float4*)&scale[col + 4];
        float4 sh0 = *(const float4*)&shift[col];
        float4 sh1 = *(const float4*)&shift[col + 4];
        f[0] = fmaxf(f[0] * sc0.x + sh0.x, 0.f);
        f[1] = fmaxf(f[1] * sc0.y + sh0.y, 0.f);
        f[2] = fmaxf(f[2] * sc0.z + sh0.z, 0.f);
        f[3] = fmaxf(f[3] * sc0.w + sh0.w, 0.f);
        f[4] = fmaxf(f[4] * sc1.x + sh1.x, 0.f);
        f[5] = fmaxf(f[5] * sc1.y + sh1.y, 0.f);
        f[6] = fmaxf(f[6] * sc1.z + sh1.z, 0.f);
        f[7] = fmaxf(f[7] * sc1.w + sh1.w, 0.f);
        uint4 o;
        o.x = (unsigned)f2bf(f[0]) | ((unsigned)f2bf(f[1]) << 16);
        o.y = (unsigned)f2bf(f[2]) | ((unsigned)f2bf(f[3]) << 16);
        o.z = (unsigned)f2bf(f[4]) | ((unsigned)f2bf(f[5]) << 16);
        o.w = (unsigned)f2bf(f[6]) | ((unsigned)f2bf(f[7]) << 16);
        ((uint4*)H)[i] = o;
    }
}

// ---------------- host ----------------

extern "C" void kernel_launch(void* const* d_in, const int* in_sizes, int n_in,
                              void* d_out, int out_size, void* d_ws, size_t ws_size,
                              hipStream_t stream) {
    const float* x = (const float*)d_in[0];
    const int* ei = (const int*)d_in[1];
    const float* w1_l = (const float*)d_in[2];
    const float* b1_l = (const float*)d_in[3];
    const float* w1_r = (const float*)d_in[4];
    const float* g1 = (const float*)d_in[5];
    const float* be1 = (const float*)d_in[6];
    const float* w2_l = (const float*)d_in[7];
    const float* b2_l = (const float*)d_in[8];
    const float* w2_r = (const float*)d_in[9];
    const float* g2 = (const float*)d_in[10];
    const float* be2 = (const float*)d_in[11];
    const float* w3_l = (const float*)d_in[12];
    const float* b3_l = (const float*)d_in[13];
    const float* w3_r = (const float*)d_in[14];
    const float* g3 = (const float*)d_in[15];
    const float* be3 = (const float*)d_in[16];
    const float* wcf = (const float*)d_in[17];
    const float* bc = (const float*)d_in[18];

    const int N = in_sizes[0] / 128;
    const int E = in_sizes[1] / 2;
    const int NB = (N + 511) >> 9;
    const int G = 256;
    const int chunk = (E + G - 1) / G;

    char* ws = (char*)d_ws;
    size_t off = 0;
    auto alloc = [&](size_t bytes) -> char* {
        char* p = ws + off;
        off += (bytes + 255) & ~(size_t)255;
        return p;
    };
    int* rp = (int*)alloc((size_t)(N + 1) * 4);
    int* csr = (int*)alloc((size_t)E * 4);
    int* flag = (int*)alloc(256);
    int* hist2 = (int*)alloc((size_t)G * NB * 4);
    int* bucketBase = (int*)alloc((size_t)(NB + 1) * 4);
    uint2* ebuf = (uint2*)alloc((size_t)E * 8);
    us* xbf = (us*)alloc((size_t)N * 128 * 2);
    us* M = (us*)alloc((size_t)N * 256 * 2);   // gather out / Yc
    us* Ha = (us*)alloc((size_t)N * 256 * 2);  // h1 raw -> relu(bn1(h1)); later h3
    us* Hb = (us*)alloc((size_t)N * 256 * 2);  // h2 raw -> relu(bn2(h2))
    float* stats = (float*)alloc(8 * 256 * 4);
    float* s0 = stats;
    float* s1 = stats + 256;
    float* scl1 = stats + 512, *shf1 = stats + 768;
    float* scl2 = stats + 1024, *shf2 = stats + 1280;
    float* scl3 = stats + 1536, *shf3 = stats + 1792;
    us* wcat1 = (us*)alloc(256 * 256 * 2);     // [256][128+128] = [w1_l | w1_r] along K
    us* wcat2 = (us*)alloc(256 * 512 * 2);     // [256][256+256] = [w2_l | w2_r] along K
    us* w3cat = (us*)alloc(256 * 256 * 2);     // rows 0-127 w3_l, 128-255 w3_r (outc concat)
    us* wc_b = (us*)alloc(16 * 128 * 2);       // row 15 padding (masked in epilogue)
    alloc(1 << 20);                             // pad: absorbs OOB staging reads
    (void)ws_size; (void)n_in; (void)out_size;

    // --- CSR build + conversions ---
    detect_i64<<<1, 1, 0, stream>>>(ei, flag);
    f32_to_bf16_kernel<<<2048, 256, 0, stream>>>(x, xbf, N * 128 / 4);
    WConvAll wc;
    wc.seg[0] = {w1_l, wcat1,       256 * 128 / 4, 5, 256};  // w4=32
    wc.seg[1] = {w1_r, wcat1 + 128, 256 * 128 / 4, 5, 256};
    wc.seg[2] = {w2_l, wcat2,       256 * 256 / 4, 6, 512};  // w4=64
    wc.seg[3] = {w2_r, wcat2 + 256, 256 * 256 / 4, 6, 512};
    wc.seg[4] = {w3_l, w3cat,             128 * 256 / 4, 6, 256};
    wc.seg[5] = {w3_r, w3cat + 128 * 256, 128 * 256 / 4, 6, 256};
    wc.seg[6] = {wcf,  wc_b,        15 * 128 / 4,  5, 128};
    conv_weights<<<256, 256, 0, stream>>>(wc);
    bucket_hist<<<G, 256, 0, stream>>>(ei, flag, E, hist2, NB, chunk);
    bucket_offsets<<<1, 256, 0, stream>>>(hist2, bucketBase, rp, N, G, NB);
    scatter8<<<G, 256, 0, stream>>>(ei, flag, E, hist2, ebuf, NB, chunk);
    fine_csr<<<NB, 256, 0, stream>>>(ebuf, bucketBase, N, rp, csr);

    const int aggGrid = (N + 3) / 4;
    const int rowTiles = (N + 127) / 128;

    // --- layer 1: 128 -> 256 ---
    agg_mean<2><<<aggGrid, 256, 0, stream>>>(xbf, rp, csr, M, N);
    gemm_mfma<128, 256, 64, 128><<<rowTiles, 256, 0, stream>>>(
        M, 128, xbf, 128, wcat1, b1_l, N, 256, Ha, nullptr);
    hipMemsetAsync(stats, 0, 2048, stream);
    bn_stats<<<1024, 256, 0, stream>>>(Ha, N, 256, s0, s1);
    bn_finalize<<<1, 256, 0, stream>>>(s0, s1, g1, be1, (float)N, 256, scl1, shf1);
    bn_apply<<<2048, 256, 0, stream>>>(Ha, N * 256 / 8, 256, scl1, shf1);  // Ha := relu(bn1(h1))

    // --- layer 2: 256 -> 256 ---
    agg_mean<4><<<aggGrid, 256, 0, stream>>>(Ha, rp, csr, M, N);
    gemm_mfma<128, 256, 64, 128><<<rowTiles, 256, 0, stream>>>(
        M, 256, Ha, 256, wcat2, b2_l, N, 256, Hb, nullptr);
    hipMemsetAsync(stats, 0, 2048, stream);
    bn_stats<<<1024, 256, 0, stream>>>(Hb, N, 256, s0, s1);
    bn_finalize<<<1, 256, 0, stream>>>(s0, s1, g2, be2, (float)N, 256, scl2, shf2);
    bn_apply<<<2048, 256, 0, stream>>>(Hb, N * 256 / 8, 256, scl2, shf2);  // Hb := relu(bn2(h2))

    // --- layer 3: GEMM-first: [Y|Z] = Hb @ [w3l;w3r]^T, then aggregate 128 cols ---
    gemm_mfma<128, 256, 64, 128><<<rowTiles, 256, 0, stream>>>(
        Hb, 256, nullptr, 0, w3cat, nullptr, N, 256, M, nullptr);
    agg_post<<<aggGrid, 256, 0, stream>>>(M, rp, csr, b3_l, Ha, N);  // Ha := h3 raw [N,128]
    hipMemsetAsync(stats, 0, 2048, stream);
    bn_stats<<<1024, 256, 0, stream>>>(Ha, N, 128, s0, s1);
    bn_finalize<<<1, 256, 0, stream>>>(s0, s1, g3, be3, (float)N, 128, scl3, shf3);
    bn_apply<<<2048, 256, 0, stream>>>(Ha, N * 128 / 8, 128, scl3, shf3);  // Ha := relu(bn3(h3))

    // --- classifier: 128 -> 15 (f32 out) ---
    gemm_mfma<128, 16, 32, 16><<<rowTiles, 256, 0, stream>>>(
        Ha, 128, nullptr, 0, wc_b, bc, N, 15, nullptr, (float*)d_out);
}

// Round 6
// 1018.757 us; speedup vs baseline: 1.1588x; 1.1588x over previous
//
#include <hip/hip_runtime.h>

// GraphSAGE 3-layer + BN(train stats) + ReLU + classifier, MI355X.
// R6: GEMM = exact m97 shape: 128x128 block (2 col-blocks for outc=256),
//     4 waves of 64x64 (acc[4][4]=64 VGPR), BK=32, 16KB LDS,
//     global_load_lds width-16 staging. R5's 64x128/wave tile (136 VGPR,
//     48KB LDS) collapsed occupancy to 8.8% -> barrier drain unhidden.
//     CSR build (R4) and BN/gather pipeline (R5) unchanged.

#define DEV static __device__ __forceinline__

typedef unsigned short us;
typedef __attribute__((ext_vector_type(8))) __bf16 bf16x8;
typedef __attribute__((ext_vector_type(4))) float f32x4;

DEV float bf2f(us u) { return __uint_as_float(((unsigned)u) << 16); }
DEV us f2bf(float f) {
    unsigned u = __float_as_uint(f);
    unsigned r = u + 0x7fffu + ((u >> 16) & 1u);  // round-nearest-even
    return (us)(r >> 16);
}

typedef __attribute__((address_space(3))) void lds_void;
typedef const __attribute__((address_space(1))) void gbl_void;
DEV void gll16(const void* g, void* l) {
    // stages 64 lanes x 16B -> LDS at (wave-uniform base) + lane*16
    __builtin_amdgcn_global_load_lds((gbl_void*)g, (lds_void*)l, 16, 0, 0);
}

// ---------------- CSR build (bucketed two-level, R4) ----------------

__global__ void detect_i64(const int* ei, int* flag) {
    int z = (ei[1] == 0) & (ei[3] == 0) & (ei[5] == 0) & (ei[7] == 0);
    *flag = z;
}

__global__ void bucket_hist(const int* __restrict__ ei, const int* __restrict__ flag,
                            int E, int* __restrict__ hist2, int NB, int chunk) {
    __shared__ int h[256];
    const int g = blockIdx.x, t = threadIdx.x;
    const bool i64 = (*flag != 0);
    h[t] = 0;
    __syncthreads();
    int beg = g * chunk, end = min(beg + chunk, E);
    for (int e = beg + t; e < end; e += 256) {
        int d = i64 ? ei[2 * (E + e)] : ei[E + e];
        atomicAdd(&h[d >> 9], 1);
    }
    __syncthreads();
    if (t < NB) hist2[g * NB + t] = h[t];
}

__global__ void bucket_offsets(int* __restrict__ hist2, int* __restrict__ bucketBase,
                               int* __restrict__ rp, int N, int G, int NB) {
    __shared__ int tot[256];
    const int t = threadIdx.x;
    int sum = 0;
    if (t < NB)
        for (int g = 0; g < G; ++g) sum += hist2[g * NB + t];
    tot[t] = sum;
    __syncthreads();
    for (int off = 1; off < 256; off <<= 1) {
        int v = (t >= off) ? tot[t - off] : 0;
        __syncthreads();
        tot[t] += v;
        __syncthreads();
    }
    int base = tot[t] - sum;
    if (t < NB) {
        bucketBase[t] = base;
        int run = base;
        for (int g = 0; g < G; ++g) {
            int v = hist2[g * NB + t];
            hist2[g * NB + t] = run;
            run += v;
        }
        if (t == NB - 1) {
            bucketBase[NB] = tot[t];
            rp[N] = tot[t];
        }
    }
}

__global__ void scatter8(const int* __restrict__ ei, const int* __restrict__ flag,
                         int E, const int* __restrict__ hist2, uint2* __restrict__ ebuf,
                         int NB, int chunk) {
    __shared__ int off[256];
    const int g = blockIdx.x, t = threadIdx.x;
    const bool i64 = (*flag != 0);
    if (t < NB) off[t] = hist2[g * NB + t];
    __syncthreads();
    int beg = g * chunk, end = min(beg + chunk, E);
    for (int e = beg + t; e < end; e += 256) {
        int s = i64 ? ei[2 * e] : ei[e];
        int d = i64 ? ei[2 * (E + e)] : ei[E + e];
        int p = atomicAdd(&off[d >> 9], 1);
        ebuf[p] = make_uint2((unsigned)s, (unsigned)d);
    }
}

__global__ void fine_csr(const uint2* __restrict__ ebuf, const int* __restrict__ bucketBase,
                         int N, int* __restrict__ rp, int* __restrict__ csr) {
    __shared__ int cnt[512];
    __shared__ int red[256];
    const int b = blockIdx.x, t = threadIdx.x;
    const int node0 = b << 9;
    cnt[t] = 0;
    cnt[t + 256] = 0;
    __syncthreads();
    const int ebeg = bucketBase[b], eend = bucketBase[b + 1];
    for (int e = ebeg + t; e < eend; e += 256) {
        uint2 r = ebuf[e];
        atomicAdd(&cnt[r.y & 511], 1);
    }
    __syncthreads();
    int c0 = cnt[2 * t], c1 = cnt[2 * t + 1];
    int s = c0 + c1;
    red[t] = s;
    __syncthreads();
    for (int off = 1; off < 256; off <<= 1) {
        int v = (t >= off) ? red[t - off] : 0;
        __syncthreads();
        red[t] += v;
        __syncthreads();
    }
    int pre = red[t] - s;
    int n0 = node0 + 2 * t;
    if (n0 < N) rp[n0] = ebeg + pre;
    if (n0 + 1 < N) rp[n0 + 1] = ebeg + pre + c0;
    __syncthreads();
    cnt[2 * t] = ebeg + pre;
    cnt[2 * t + 1] = ebeg + pre + c0;
    __syncthreads();
    for (int e = ebeg + t; e < eend; e += 256) {
        uint2 r = ebuf[e];
        int p = atomicAdd(&cnt[r.y & 511], 1);
        csr[p] = (int)r.x;
    }
}

// ---------------- dtype convert / weight concat ----------------

__global__ void f32_to_bf16_kernel(const float* __restrict__ x, us* __restrict__ o, int n4) {
    for (int i = blockIdx.x * blockDim.x + threadIdx.x; i < n4; i += gridDim.x * blockDim.x) {
        float4 v = ((const float4*)x)[i];
        ushort4 r;
        r.x = f2bf(v.x); r.y = f2bf(v.y); r.z = f2bf(v.z); r.w = f2bf(v.w);
        ((ushort4*)o)[i] = r;
    }
}

struct WSeg { const float* s; us* d; int n4; int l2w4; int stride; };
struct WConvAll { WSeg seg[7]; };

__global__ void conv_weights(WConvAll wc) {
    for (int sg = 0; sg < 7; ++sg) {
        WSeg w = wc.seg[sg];
        for (int i = blockIdx.x * blockDim.x + threadIdx.x; i < w.n4; i += gridDim.x * blockDim.x) {
            float4 v = ((const float4*)w.s)[i];
            ushort4 r;
            r.x = f2bf(v.x); r.y = f2bf(v.y); r.z = f2bf(v.z); r.w = f2bf(v.w);
            int row = i >> w.l2w4;
            int col = (i - (row << w.l2w4)) * 4;
            *(ushort4*)(w.d + (size_t)row * w.stride + col) = r;
        }
    }
}

// ---------------- mean aggregation (wave per node) ----------------

template <int VEC>  // cols = 64*VEC
__global__ void agg_mean(const us* __restrict__ X, const int* __restrict__ rp,
                         const int* __restrict__ csr, us* __restrict__ M, int n) {
    const int cols = VEC * 64;
    int w = blockIdx.x * (blockDim.x >> 6) + (threadIdx.x >> 6);
    int lane = threadIdx.x & 63;
    if (w >= n) return;
    int beg = rp[w], end = rp[w + 1];
    float acc[VEC];
#pragma unroll
    for (int i = 0; i < VEC; ++i) acc[i] = 0.f;
    int e = beg;
    for (; e + 2 <= end; e += 2) {
        int j0 = csr[e], j1 = csr[e + 1];
        if (VEC == 2) {
            unsigned u0 = *(const unsigned*)(X + (size_t)j0 * cols + lane * 2);
            unsigned u1 = *(const unsigned*)(X + (size_t)j1 * cols + lane * 2);
            acc[0] += __uint_as_float(u0 << 16) + __uint_as_float(u1 << 16);
            acc[1] += __uint_as_float(u0 & 0xffff0000u) + __uint_as_float(u1 & 0xffff0000u);
        } else {
            uint2 u0 = *(const uint2*)(X + (size_t)j0 * cols + lane * 4);
            uint2 u1 = *(const uint2*)(X + (size_t)j1 * cols + lane * 4);
            acc[0] += __uint_as_float(u0.x << 16) + __uint_as_float(u1.x << 16);
            acc[1] += __uint_as_float(u0.x & 0xffff0000u) + __uint_as_float(u1.x & 0xffff0000u);
            acc[2] += __uint_as_float(u0.y << 16) + __uint_as_float(u1.y << 16);
            acc[3] += __uint_as_float(u0.y & 0xffff0000u) + __uint_as_float(u1.y & 0xffff0000u);
        }
    }
    if (e < end) {
        int j0 = csr[e];
        if (VEC == 2) {
            unsigned u0 = *(const unsigned*)(X + (size_t)j0 * cols + lane * 2);
            acc[0] += __uint_as_float(u0 << 16);
            acc[1] += __uint_as_float(u0 & 0xffff0000u);
        } else {
            uint2 u0 = *(const uint2*)(X + (size_t)j0 * cols + lane * 4);
            acc[0] += __uint_as_float(u0.x << 16);
            acc[1] += __uint_as_float(u0.x & 0xffff0000u);
            acc[2] += __uint_as_float(u0.y << 16);
            acc[3] += __uint_as_float(u0.y & 0xffff0000u);
        }
    }
    float inv = 1.0f / (float)max(end - beg, 1);
    us* q = M + (size_t)w * cols + lane * VEC;
    if (VEC == 2) {
        *(ushort2*)q = make_ushort2(f2bf(acc[0] * inv), f2bf(acc[1] * inv));
    } else {
        *(ushort4*)q = make_ushort4(f2bf(acc[0] * inv), f2bf(acc[1] * inv),
                                    f2bf(acc[2] * inv), f2bf(acc[3] * inv));
    }
}

// layer-3 post-GEMM aggregation: H[i][c] = mean_j Yc[j][c] + Yc[i][128+c] + bias[c]
__global__ void agg_post(const us* __restrict__ Yc, const int* __restrict__ rp,
                         const int* __restrict__ csr, const float* __restrict__ bias,
                         us* __restrict__ H, int n) {
    int w = blockIdx.x * (blockDim.x >> 6) + (threadIdx.x >> 6);
    int lane = threadIdx.x & 63;
    if (w >= n) return;
    int beg = rp[w], end = rp[w + 1];
    float a0 = 0.f, a1 = 0.f;
    int e = beg;
    for (; e + 2 <= end; e += 2) {
        int j0 = csr[e], j1 = csr[e + 1];
        unsigned u0 = *(const unsigned*)(Yc + (size_t)j0 * 256 + lane * 2);
        unsigned u1 = *(const unsigned*)(Yc + (size_t)j1 * 256 + lane * 2);
        a0 += __uint_as_float(u0 << 16) + __uint_as_float(u1 << 16);
        a1 += __uint_as_float(u0 & 0xffff0000u) + __uint_as_float(u1 & 0xffff0000u);
    }
    if (e < end) {
        unsigned u0 = *(const unsigned*)(Yc + (size_t)csr[e] * 256 + lane * 2);
        a0 += __uint_as_float(u0 << 16);
        a1 += __uint_as_float(u0 & 0xffff0000u);
    }
    float inv = 1.0f / (float)max(end - beg, 1);
    unsigned uz = *(const unsigned*)(Yc + (size_t)w * 256 + 128 + lane * 2);
    float2 bv = *(const float2*)(bias + lane * 2);
    float r0 = a0 * inv + __uint_as_float(uz << 16) + bv.x;
    float r1 = a1 * inv + __uint_as_float(uz & 0xffff0000u) + bv.y;
    *(ushort2*)(H + (size_t)w * 128 + lane * 2) = make_ushort2(f2bf(r0), f2bf(r1));
}

// ---------------- MFMA GEMM (m97 shape), K-concat dual source, DMA staging ----
// C = [A0|A1] @ W^T + bias. BK=32. Block BM x BN, 4 waves of WM x WN.
// LDS fragment layout: 1KB per 16-row tile: base + lane*16 (lane = row%16 | k-quad).

template <int BM, int BN, int WM, int WN>
__launch_bounds__(256)
__global__ void gemm_mfma(const us* __restrict__ A0, int K0,
                          const us* __restrict__ A1, int K1,
                          const us* __restrict__ W, const float* __restrict__ bias,
                          int n, int outc, us* __restrict__ Cbf, float* __restrict__ Cf) {
    constexpr int MT = WM / 16;
    constexpr int NT = WN / 16;
    constexpr int WCols = BN / WN;
    __shared__ __align__(16) us As[BM * 32];
    __shared__ __align__(16) us Bs[BN * 32];

    const int t = threadIdx.x;
    const int wid = t >> 6, lane = t & 63;
    const int wr = wid / WCols, wcc = wid % WCols;
    const int row0 = blockIdx.x * BM;
    const int col0 = blockIdx.y * BN;
    const int Kp = K0 + K1;
    const int l15 = lane & 15, l4 = lane >> 4;

    f32x4 acc[MT][NT];
#pragma unroll
    for (int i = 0; i < MT; ++i)
#pragma unroll
        for (int j = 0; j < NT; ++j) acc[i][j] = (f32x4){0.f, 0.f, 0.f, 0.f};

    for (int kc = 0; kc < Kp; kc += 32) {
        const us* A = (kc < K0) ? A0 : A1;
        const int rs = (kc < K0) ? K0 : K1;
        const int ko = (kc < K0) ? kc : kc - K0;
        // stage A: blk = 16-row tile; lane l: row=(blk*16+(l&15)), k=ko+(l>>4)*8
#pragma unroll
        for (int c = t; c < BM * 4; c += 256) {
            int blk = c >> 6;
            int row = row0 + (blk << 4) + l15;
            gll16(A + (size_t)row * rs + ko + (l4 << 3), (char*)As + blk * 1024 + lane * 16);
        }
#pragma unroll
        for (int c = t; c < BN * 4; c += 256) {
            int blk = c >> 6;
            int col = col0 + (blk << 4) + l15;
            gll16(W + (size_t)col * Kp + kc + (l4 << 3), (char*)Bs + blk * 1024 + lane * 16);
        }
        __syncthreads();
        bf16x8 af[MT], bfr[NT];
#pragma unroll
        for (int mt = 0; mt < MT; ++mt)
            af[mt] = *(const bf16x8*)((char*)As + (wr * MT + mt) * 1024 + lane * 16);
#pragma unroll
        for (int nt = 0; nt < NT; ++nt)
            bfr[nt] = *(const bf16x8*)((char*)Bs + (wcc * NT + nt) * 1024 + lane * 16);
#pragma unroll
        for (int mt = 0; mt < MT; ++mt)
#pragma unroll
            for (int nt = 0; nt < NT; ++nt)
                acc[mt][nt] = __builtin_amdgcn_mfma_f32_16x16x32_bf16(af[mt], bfr[nt], acc[mt][nt], 0, 0, 0);
        __syncthreads();
    }

    // epilogue: C/D map col=lane&15, row=(lane>>4)*4+reg
#pragma unroll
    for (int mt = 0; mt < MT; ++mt) {
#pragma unroll
        for (int nt = 0; nt < NT; ++nt) {
            int col = col0 + wcc * WN + nt * 16 + l15;
            int rbase = row0 + wr * WM + mt * 16 + (l4 << 2);
            bool cok = col < outc;
            float bv = (bias != nullptr && cok) ? bias[col] : 0.f;
#pragma unroll
            for (int i = 0; i < 4; ++i) {
                int r = rbase + i;
                if (r < n && cok) {
                    float v = acc[mt][nt][i] + bv;
                    if (Cf) Cf[(size_t)r * outc + col] = v;
                    else Cbf[(size_t)r * outc + col] = f2bf(v);
                }
            }
        }
    }
}

// ---------------- BatchNorm ----------------

__global__ void bn_stats(const us* __restrict__ H, int n, int c,
                         float* __restrict__ s0, float* __restrict__ s1) {
    int col = threadIdx.x;
    if (col >= c) return;
    float s = 0.f, q = 0.f;
    for (int r = blockIdx.x; r < n; r += gridDim.x) {
        float v = bf2f(H[(size_t)r * c + col]);
        s += v;
        q += v * v;
    }
    atomicAdd(&s0[col], s);
    atomicAdd(&s1[col], q);
}

__global__ void bn_finalize(const float* __restrict__ s0, const float* __restrict__ s1,
                            const float* __restrict__ g, const float* __restrict__ be,
                            float fn, int c, float* __restrict__ scale, float* __restrict__ shift) {
    int col = threadIdx.x;
    if (col >= c) return;
    float mean = s0[col] / fn;
    float var = s1[col] / fn - mean * mean;
    float sc = g[col] * rsqrtf(var + 1e-5f);
    scale[col] = sc;
    shift[col] = be[col] - mean * sc;
}

__global__ void bn_apply(us* __restrict__ H, int n8, int c,
                         const float* __restrict__ scale, const float* __restrict__ shift) {
    int cdiv8 = c >> 3;
    for (int i = blockIdx.x * blockDim.x + threadIdx.x; i < n8; i += gridDim.x * blockDim.x) {
        int col = (i % cdiv8) << 3;
        uint4 v = ((const uint4*)H)[i];
        float f[8];
        f[0] = __uint_as_float(v.x << 16); f[1] = __uint_as_float(v.x & 0xffff0000u);
        f[2] = __uint_as_float(v.y << 16); f[3] = __uint_as_float(v.y & 0xffff0000u);
        f[4] = __uint_as_float(v.z << 16); f[5] = __uint_as_float(v.z & 0xffff0000u);
        f[6] = __uint_as_float(v.w << 16); f[7] = __uint_as_float(v.w & 0xffff0000u);
        float4 sc0 = *(const float4*)&scale[col];
        float4 sc1 = *(const float4*)&scale[col + 4];
        float4 sh0 = *(const float4*)&shift[col];
        float4 sh1 = *(const float4*)&shift[col + 4];
        f[0] = fmaxf(f[0] * sc0.x + sh0.x, 0.f);
        f[1] = fmaxf(f[1] * sc0.y + sh0.y, 0.f);
        f[2] = fmaxf(f[2] * sc0.z + sh0.z, 0.f);
        f[3] = fmaxf(f[3] * sc0.w + sh0.w, 0.f);
        f[4] = fmaxf(f[4] * sc1.x + sh1.x, 0.f);
        f[5] = fmaxf(f[5] * sc1.y + sh1.y, 0.f);
        f[6] = fmaxf(f[6] * sc1.z + sh1.z, 0.f);
        f[7] = fmaxf(f[7] * sc1.w + sh1.w, 0.f);
        uint4 o;
        o.x = (unsigned)f2bf(f[0]) | ((unsigned)f2bf(f[1]) << 16);
        o.y = (unsigned)f2bf(f[2]) | ((unsigned)f2bf(f[3]) << 16);
        o.z = (unsigned)f2bf(f[4]) | ((unsigned)f2bf(f[5]) << 16);
        o.w = (unsigned)f2bf(f[6]) | ((unsigned)f2bf(f[7]) << 16);
        ((uint4*)H)[i] = o;
    }
}

// ---------------- host ----------------

extern "C" void kernel_launch(void* const* d_in, const int* in_sizes, int n_in,
                              void* d_out, int out_size, void* d_ws, size_t ws_size,
                              hipStream_t stream) {
    const float* x = (const float*)d_in[0];
    const int* ei = (const int*)d_in[1];
    const float* w1_l = (const float*)d_in[2];
    const float* b1_l = (const float*)d_in[3];
    const float* w1_r = (const float*)d_in[4];
    const float* g1 = (const float*)d_in[5];
    const float* be1 = (const float*)d_in[6];
    const float* w2_l = (const float*)d_in[7];
    const float* b2_l = (const float*)d_in[8];
    const float* w2_r = (const float*)d_in[9];
    const float* g2 = (const float*)d_in[10];
    const float* be2 = (const float*)d_in[11];
    const float* w3_l = (const float*)d_in[12];
    const float* b3_l = (const float*)d_in[13];
    const float* w3_r = (const float*)d_in[14];
    const float* g3 = (const float*)d_in[15];
    const float* be3 = (const float*)d_in[16];
    const float* wcf = (const float*)d_in[17];
    const float* bc = (const float*)d_in[18];

    const int N = in_sizes[0] / 128;
    const int E = in_sizes[1] / 2;
    const int NB = (N + 511) >> 9;
    const int G = 256;
    const int chunk = (E + G - 1) / G;

    char* ws = (char*)d_ws;
    size_t off = 0;
    auto alloc = [&](size_t bytes) -> char* {
        char* p = ws + off;
        off += (bytes + 255) & ~(size_t)255;
        return p;
    };
    int* rp = (int*)alloc((size_t)(N + 1) * 4);
    int* csr = (int*)alloc((size_t)E * 4);
    int* flag = (int*)alloc(256);
    int* hist2 = (int*)alloc((size_t)G * NB * 4);
    int* bucketBase = (int*)alloc((size_t)(NB + 1) * 4);
    uint2* ebuf = (uint2*)alloc((size_t)E * 8);
    us* xbf = (us*)alloc((size_t)N * 128 * 2);
    us* M = (us*)alloc((size_t)N * 256 * 2);   // gather out / Yc
    us* Ha = (us*)alloc((size_t)N * 256 * 2);  // h1 raw -> relu(bn1(h1)); later h3
    us* Hb = (us*)alloc((size_t)N * 256 * 2);  // h2 raw -> relu(bn2(h2))
    float* stats = (float*)alloc(8 * 256 * 4);
    float* s0 = stats;
    float* s1 = stats + 256;
    float* scl1 = stats + 512, *shf1 = stats + 768;
    float* scl2 = stats + 1024, *shf2 = stats + 1280;
    float* scl3 = stats + 1536, *shf3 = stats + 1792;
    us* wcat1 = (us*)alloc(256 * 256 * 2);     // [256][128+128] = [w1_l | w1_r] along K
    us* wcat2 = (us*)alloc(256 * 512 * 2);     // [256][256+256] = [w2_l | w2_r] along K
    us* w3cat = (us*)alloc(256 * 256 * 2);     // rows 0-127 w3_l, 128-255 w3_r
    us* wc_b = (us*)alloc(16 * 128 * 2);       // row 15 padding (masked in epilogue)
    alloc(1 << 20);                             // pad: absorbs OOB staging reads
    (void)ws_size; (void)n_in; (void)out_size;

    // --- CSR build + conversions ---
    detect_i64<<<1, 1, 0, stream>>>(ei, flag);
    f32_to_bf16_kernel<<<2048, 256, 0, stream>>>(x, xbf, N * 128 / 4);
    WConvAll wc;
    wc.seg[0] = {w1_l, wcat1,       256 * 128 / 4, 5, 256};
    wc.seg[1] = {w1_r, wcat1 + 128, 256 * 128 / 4, 5, 256};
    wc.seg[2] = {w2_l, wcat2,       256 * 256 / 4, 6, 512};
    wc.seg[3] = {w2_r, wcat2 + 256, 256 * 256 / 4, 6, 512};
    wc.seg[4] = {w3_l, w3cat,             128 * 256 / 4, 6, 256};
    wc.seg[5] = {w3_r, w3cat + 128 * 256, 128 * 256 / 4, 6, 256};
    wc.seg[6] = {wcf,  wc_b,        15 * 128 / 4,  5, 128};
    conv_weights<<<256, 256, 0, stream>>>(wc);
    bucket_hist<<<G, 256, 0, stream>>>(ei, flag, E, hist2, NB, chunk);
    bucket_offsets<<<1, 256, 0, stream>>>(hist2, bucketBase, rp, N, G, NB);
    scatter8<<<G, 256, 0, stream>>>(ei, flag, E, hist2, ebuf, NB, chunk);
    fine_csr<<<NB, 256, 0, stream>>>(ebuf, bucketBase, N, rp, csr);

    const int aggGrid = (N + 3) / 4;
    const int rowTiles = (N + 127) / 128;

    // --- layer 1: 128 -> 256 ---
    agg_mean<2><<<aggGrid, 256, 0, stream>>>(xbf, rp, csr, M, N);
    gemm_mfma<128, 128, 64, 64><<<dim3(rowTiles, 2), 256, 0, stream>>>(
        M, 128, xbf, 128, wcat1, b1_l, N, 256, Ha, nullptr);
    hipMemsetAsync(stats, 0, 2048, stream);
    bn_stats<<<1024, 256, 0, stream>>>(Ha, N, 256, s0, s1);
    bn_finalize<<<1, 256, 0, stream>>>(s0, s1, g1, be1, (float)N, 256, scl1, shf1);
    bn_apply<<<2048, 256, 0, stream>>>(Ha, N * 256 / 8, 256, scl1, shf1);

    // --- layer 2: 256 -> 256 ---
    agg_mean<4><<<aggGrid, 256, 0, stream>>>(Ha, rp, csr, M, N);
    gemm_mfma<128, 128, 64, 64><<<dim3(rowTiles, 2), 256, 0, stream>>>(
        M, 256, Ha, 256, wcat2, b2_l, N, 256, Hb, nullptr);
    hipMemsetAsync(stats, 0, 2048, stream);
    bn_stats<<<1024, 256, 0, stream>>>(Hb, N, 256, s0, s1);
    bn_finalize<<<1, 256, 0, stream>>>(s0, s1, g2, be2, (float)N, 256, scl2, shf2);
    bn_apply<<<2048, 256, 0, stream>>>(Hb, N * 256 / 8, 256, scl2, shf2);

    // --- layer 3: GEMM-first: [Y|Z] = Hb @ [w3l;w3r]^T, then aggregate 128 cols ---
    gemm_mfma<128, 128, 64, 64><<<dim3(rowTiles, 2), 256, 0, stream>>>(
        Hb, 256, nullptr, 0, w3cat, nullptr, N, 256, M, nullptr);
    agg_post<<<aggGrid, 256, 0, stream>>>(M, rp, csr, b3_l, Ha, N);
    hipMemsetAsync(stats, 0, 2048, stream);
    bn_stats<<<1024, 256, 0, stream>>>(Ha, N, 128, s0, s1);
    bn_finalize<<<1, 256, 0, stream>>>(s0, s1, g3, be3, (float)N, 128, scl3, shf3);
    bn_apply<<<2048, 256, 0, stream>>>(Ha, N * 128 / 8, 128, scl3, shf3);

    // --- classifier: 128 -> 15 (f32 out) ---
    gemm_mfma<128, 16, 32, 16><<<dim3(rowTiles, 1), 256, 0, stream>>>(
        Ha, 128, nullptr, 0, wc_b, bc, N, 15, nullptr, (float*)d_out);
}

// Round 7
// 909.237 us; speedup vs baseline: 1.2984x; 1.1205x over previous
//
#include <hip/hip_runtime.h>

// GraphSAGE 3-layer + BN(train stats) + ReLU + classifier, MI355X.
// R7: unroll-4 gathers (latency-bound: 4 edges in flight), bn_stats fused
//     into GEMM epilogue (L1/L2), bn_finalize folded into bn_apply,
//     detect_i64 inlined, x-convert merged into weight conversion,
//     single upfront stats memset. GEMM core (R6 m97-shape) unchanged.

#define DEV static __device__ __forceinline__

typedef unsigned short us;
typedef __attribute__((ext_vector_type(8))) __bf16 bf16x8;
typedef __attribute__((ext_vector_type(4))) float f32x4;

DEV float bf2f(us u) { return __uint_as_float(((unsigned)u) << 16); }
DEV us f2bf(float f) {
    unsigned u = __float_as_uint(f);
    unsigned r = u + 0x7fffu + ((u >> 16) & 1u);  // round-nearest-even
    return (us)(r >> 16);
}

typedef __attribute__((address_space(3))) void lds_void;
typedef const __attribute__((address_space(1))) void gbl_void;
DEV void gll16(const void* g, void* l) {
    __builtin_amdgcn_global_load_lds((gbl_void*)g, (lds_void*)l, 16, 0, 0);
}

DEV bool is_i64(const int* ei) {
    return (ei[1] == 0) & (ei[3] == 0) & (ei[5] == 0) & (ei[7] == 0);
}

// ---------------- CSR build (bucketed two-level) ----------------

__global__ void bucket_hist(const int* __restrict__ ei, int E, int* __restrict__ hist2,
                            int NB, int chunk) {
    __shared__ int h[256];
    const int g = blockIdx.x, t = threadIdx.x;
    const bool i64 = is_i64(ei);
    h[t] = 0;
    __syncthreads();
    int beg = g * chunk, end = min(beg + chunk, E);
    for (int e = beg + t; e < end; e += 256) {
        int d = i64 ? ei[2 * (E + e)] : ei[E + e];
        atomicAdd(&h[d >> 9], 1);
    }
    __syncthreads();
    if (t < NB) hist2[g * NB + t] = h[t];
}

__global__ void bucket_offsets(int* __restrict__ hist2, int* __restrict__ bucketBase,
                               int* __restrict__ rp, int N, int G, int NB) {
    __shared__ int tot[256];
    const int t = threadIdx.x;
    int sum = 0;
    if (t < NB)
        for (int g = 0; g < G; ++g) sum += hist2[g * NB + t];
    tot[t] = sum;
    __syncthreads();
    for (int off = 1; off < 256; off <<= 1) {
        int v = (t >= off) ? tot[t - off] : 0;
        __syncthreads();
        tot[t] += v;
        __syncthreads();
    }
    int base = tot[t] - sum;
    if (t < NB) {
        bucketBase[t] = base;
        int run = base;
        for (int g = 0; g < G; ++g) {
            int v = hist2[g * NB + t];
            hist2[g * NB + t] = run;
            run += v;
        }
        if (t == NB - 1) {
            bucketBase[NB] = tot[t];
            rp[N] = tot[t];
        }
    }
}

__global__ void scatter8(const int* __restrict__ ei, int E, const int* __restrict__ hist2,
                         uint2* __restrict__ ebuf, int NB, int chunk) {
    __shared__ int off[256];
    const int g = blockIdx.x, t = threadIdx.x;
    const bool i64 = is_i64(ei);
    if (t < NB) off[t] = hist2[g * NB + t];
    __syncthreads();
    int beg = g * chunk, end = min(beg + chunk, E);
    for (int e = beg + t; e < end; e += 256) {
        int s = i64 ? ei[2 * e] : ei[e];
        int d = i64 ? ei[2 * (E + e)] : ei[E + e];
        int p = atomicAdd(&off[d >> 9], 1);
        ebuf[p] = make_uint2((unsigned)s, (unsigned)d);
    }
}

__global__ void fine_csr(const uint2* __restrict__ ebuf, const int* __restrict__ bucketBase,
                         int N, int* __restrict__ rp, int* __restrict__ csr) {
    __shared__ int cnt[512];
    __shared__ int red[256];
    const int b = blockIdx.x, t = threadIdx.x;
    const int node0 = b << 9;
    cnt[t] = 0;
    cnt[t + 256] = 0;
    __syncthreads();
    const int ebeg = bucketBase[b], eend = bucketBase[b + 1];
    for (int e = ebeg + t; e < eend; e += 256) {
        uint2 r = ebuf[e];
        atomicAdd(&cnt[r.y & 511], 1);
    }
    __syncthreads();
    int c0 = cnt[2 * t], c1 = cnt[2 * t + 1];
    int s = c0 + c1;
    red[t] = s;
    __syncthreads();
    for (int off = 1; off < 256; off <<= 1) {
        int v = (t >= off) ? red[t - off] : 0;
        __syncthreads();
        red[t] += v;
        __syncthreads();
    }
    int pre = red[t] - s;
    int n0 = node0 + 2 * t;
    if (n0 < N) rp[n0] = ebeg + pre;
    if (n0 + 1 < N) rp[n0 + 1] = ebeg + pre + c0;
    __syncthreads();
    cnt[2 * t] = ebeg + pre;
    cnt[2 * t + 1] = ebeg + pre + c0;
    __syncthreads();
    for (int e = ebeg + t; e < eend; e += 256) {
        uint2 r = ebuf[e];
        int p = atomicAdd(&cnt[r.y & 511], 1);
        csr[p] = (int)r.x;
    }
}

// ---------------- f32 -> bf16 conversion (x + all weights, one kernel) ----

struct WSeg { const float* s; us* d; int n4; int l2w4; int stride; };
struct WConvAll { WSeg seg[8]; };

__global__ void conv_all(WConvAll wc) {
    for (int sg = 0; sg < 8; ++sg) {
        WSeg w = wc.seg[sg];
        for (int i = blockIdx.x * blockDim.x + threadIdx.x; i < w.n4; i += gridDim.x * blockDim.x) {
            float4 v = ((const float4*)w.s)[i];
            ushort4 r;
            r.x = f2bf(v.x); r.y = f2bf(v.y); r.z = f2bf(v.z); r.w = f2bf(v.w);
            int row = i >> w.l2w4;
            int col = (i - (row << w.l2w4)) * 4;
            *(ushort4*)(w.d + (size_t)row * w.stride + col) = r;
        }
    }
}

// ---------------- mean aggregation (wave per node, unroll-4) ----------------

template <int VEC>  // cols = 64*VEC
__global__ void agg_mean(const us* __restrict__ X, const int* __restrict__ rp,
                         const int* __restrict__ csr, us* __restrict__ M, int n) {
    const int cols = VEC * 64;
    int w = blockIdx.x * (blockDim.x >> 6) + (threadIdx.x >> 6);
    int lane = threadIdx.x & 63;
    if (w >= n) return;
    int beg = rp[w], end = rp[w + 1];
    const us* Xb = X + lane * VEC;
    float acc[VEC];
#pragma unroll
    for (int i = 0; i < VEC; ++i) acc[i] = 0.f;
    int e = beg;
    for (; e + 4 <= end; e += 4) {
        int j0 = csr[e], j1 = csr[e + 1], j2 = csr[e + 2], j3 = csr[e + 3];
        if (VEC == 2) {
            unsigned u0 = *(const unsigned*)(Xb + (size_t)j0 * cols);
            unsigned u1 = *(const unsigned*)(Xb + (size_t)j1 * cols);
            unsigned u2 = *(const unsigned*)(Xb + (size_t)j2 * cols);
            unsigned u3 = *(const unsigned*)(Xb + (size_t)j3 * cols);
            acc[0] += __uint_as_float(u0 << 16) + __uint_as_float(u1 << 16)
                    + __uint_as_float(u2 << 16) + __uint_as_float(u3 << 16);
            acc[1] += __uint_as_float(u0 & 0xffff0000u) + __uint_as_float(u1 & 0xffff0000u)
                    + __uint_as_float(u2 & 0xffff0000u) + __uint_as_float(u3 & 0xffff0000u);
        } else {
            uint2 u0 = *(const uint2*)(Xb + (size_t)j0 * cols);
            uint2 u1 = *(const uint2*)(Xb + (size_t)j1 * cols);
            uint2 u2 = *(const uint2*)(Xb + (size_t)j2 * cols);
            uint2 u3 = *(const uint2*)(Xb + (size_t)j3 * cols);
            acc[0] += __uint_as_float(u0.x << 16) + __uint_as_float(u1.x << 16)
                    + __uint_as_float(u2.x << 16) + __uint_as_float(u3.x << 16);
            acc[1] += __uint_as_float(u0.x & 0xffff0000u) + __uint_as_float(u1.x & 0xffff0000u)
                    + __uint_as_float(u2.x & 0xffff0000u) + __uint_as_float(u3.x & 0xffff0000u);
            acc[2] += __uint_as_float(u0.y << 16) + __uint_as_float(u1.y << 16)
                    + __uint_as_float(u2.y << 16) + __uint_as_float(u3.y << 16);
            acc[3] += __uint_as_float(u0.y & 0xffff0000u) + __uint_as_float(u1.y & 0xffff0000u)
                    + __uint_as_float(u2.y & 0xffff0000u) + __uint_as_float(u3.y & 0xffff0000u);
        }
    }
    for (; e < end; ++e) {
        int j0 = csr[e];
        if (VEC == 2) {
            unsigned u0 = *(const unsigned*)(Xb + (size_t)j0 * cols);
            acc[0] += __uint_as_float(u0 << 16);
            acc[1] += __uint_as_float(u0 & 0xffff0000u);
        } else {
            uint2 u0 = *(const uint2*)(Xb + (size_t)j0 * cols);
            acc[0] += __uint_as_float(u0.x << 16);
            acc[1] += __uint_as_float(u0.x & 0xffff0000u);
            acc[2] += __uint_as_float(u0.y << 16);
            acc[3] += __uint_as_float(u0.y & 0xffff0000u);
        }
    }
    float inv = 1.0f / (float)max(end - beg, 1);
    us* q = M + (size_t)w * cols + lane * VEC;
    if (VEC == 2) {
        *(ushort2*)q = make_ushort2(f2bf(acc[0] * inv), f2bf(acc[1] * inv));
    } else {
        *(ushort4*)q = make_ushort4(f2bf(acc[0] * inv), f2bf(acc[1] * inv),
                                    f2bf(acc[2] * inv), f2bf(acc[3] * inv));
    }
}

// layer-3 post-GEMM aggregation (unroll-4): H[i][c] = mean_j Yc[j][c] + Yc[i][128+c] + b[c]
__global__ void agg_post(const us* __restrict__ Yc, const int* __restrict__ rp,
                         const int* __restrict__ csr, const float* __restrict__ bias,
                         us* __restrict__ H, int n) {
    int w = blockIdx.x * (blockDim.x >> 6) + (threadIdx.x >> 6);
    int lane = threadIdx.x & 63;
    if (w >= n) return;
    int beg = rp[w], end = rp[w + 1];
    const us* Yb = Yc + lane * 2;
    float a0 = 0.f, a1 = 0.f;
    int e = beg;
    for (; e + 4 <= end; e += 4) {
        int j0 = csr[e], j1 = csr[e + 1], j2 = csr[e + 2], j3 = csr[e + 3];
        unsigned u0 = *(const unsigned*)(Yb + (size_t)j0 * 256);
        unsigned u1 = *(const unsigned*)(Yb + (size_t)j1 * 256);
        unsigned u2 = *(const unsigned*)(Yb + (size_t)j2 * 256);
        unsigned u3 = *(const unsigned*)(Yb + (size_t)j3 * 256);
        a0 += __uint_as_float(u0 << 16) + __uint_as_float(u1 << 16)
            + __uint_as_float(u2 << 16) + __uint_as_float(u3 << 16);
        a1 += __uint_as_float(u0 & 0xffff0000u) + __uint_as_float(u1 & 0xffff0000u)
            + __uint_as_float(u2 & 0xffff0000u) + __uint_as_float(u3 & 0xffff0000u);
    }
    for (; e < end; ++e) {
        unsigned u0 = *(const unsigned*)(Yb + (size_t)csr[e] * 256);
        a0 += __uint_as_float(u0 << 16);
        a1 += __uint_as_float(u0 & 0xffff0000u);
    }
    float inv = 1.0f / (float)max(end - beg, 1);
    unsigned uz = *(const unsigned*)(Yc + (size_t)w * 256 + 128 + lane * 2);
    float2 bv = *(const float2*)(bias + lane * 2);
    float r0 = a0 * inv + __uint_as_float(uz << 16) + bv.x;
    float r1 = a1 * inv + __uint_as_float(uz & 0xffff0000u) + bv.y;
    *(ushort2*)(H + (size_t)w * 128 + lane * 2) = make_ushort2(f2bf(r0), f2bf(r1));
}

// ---------------- MFMA GEMM (m97 shape) + optional fused BN-stats epilogue ----
// C = [A0|A1] @ W^T + bias; if st0: atomically accumulate col sum/sumsq of C.

template <int BM, int BN, int WM, int WN>
__launch_bounds__(256)
__global__ void gemm_mfma(const us* __restrict__ A0, int K0,
                          const us* __restrict__ A1, int K1,
                          const us* __restrict__ W, const float* __restrict__ bias,
                          int n, int outc, us* __restrict__ Cbf, float* __restrict__ Cf,
                          float* __restrict__ st0, float* __restrict__ st1) {
    constexpr int MT = WM / 16;
    constexpr int NT = WN / 16;
    constexpr int WCols = BN / WN;
    __shared__ __align__(16) us As[BM * 32];
    __shared__ __align__(16) us Bs[BN * 32];
    __shared__ float colred[2][BN];

    const int t = threadIdx.x;
    const int wid = t >> 6, lane = t & 63;
    const int wr = wid / WCols, wcc = wid % WCols;
    const int row0 = blockIdx.x * BM;
    const int col0 = blockIdx.y * BN;
    const int Kp = K0 + K1;
    const int l15 = lane & 15, l4 = lane >> 4;

    f32x4 acc[MT][NT];
#pragma unroll
    for (int i = 0; i < MT; ++i)
#pragma unroll
        for (int j = 0; j < NT; ++j) acc[i][j] = (f32x4){0.f, 0.f, 0.f, 0.f};

    for (int kc = 0; kc < Kp; kc += 32) {
        const us* A = (kc < K0) ? A0 : A1;
        const int rs = (kc < K0) ? K0 : K1;
        const int ko = (kc < K0) ? kc : kc - K0;
#pragma unroll
        for (int c = t; c < BM * 4; c += 256) {
            int blk = c >> 6;
            int row = row0 + (blk << 4) + l15;
            gll16(A + (size_t)row * rs + ko + (l4 << 3), (char*)As + blk * 1024 + lane * 16);
        }
#pragma unroll
        for (int c = t; c < BN * 4; c += 256) {
            int blk = c >> 6;
            int col = col0 + (blk << 4) + l15;
            gll16(W + (size_t)col * Kp + kc + (l4 << 3), (char*)Bs + blk * 1024 + lane * 16);
        }
        __syncthreads();
        bf16x8 af[MT], bfr[NT];
#pragma unroll
        for (int mt = 0; mt < MT; ++mt)
            af[mt] = *(const bf16x8*)((char*)As + (wr * MT + mt) * 1024 + lane * 16);
#pragma unroll
        for (int nt = 0; nt < NT; ++nt)
            bfr[nt] = *(const bf16x8*)((char*)Bs + (wcc * NT + nt) * 1024 + lane * 16);
#pragma unroll
        for (int mt = 0; mt < MT; ++mt)
#pragma unroll
            for (int nt = 0; nt < NT; ++nt)
                acc[mt][nt] = __builtin_amdgcn_mfma_f32_16x16x32_bf16(af[mt], bfr[nt], acc[mt][nt], 0, 0, 0);
        __syncthreads();
    }

    if (st0) {
#pragma unroll
        for (int c = t; c < 2 * BN; c += 256) (&colred[0][0])[c] = 0.f;
        __syncthreads();
    }

    // epilogue: C/D map col=lane&15, row=(lane>>4)*4+reg
#pragma unroll
    for (int nt = 0; nt < NT; ++nt) {
        int col = col0 + wcc * WN + nt * 16 + l15;
        bool cok = col < outc;
        float bv = (bias != nullptr && cok) ? bias[col] : 0.f;
        float ls = 0.f, lq = 0.f;
#pragma unroll
        for (int mt = 0; mt < MT; ++mt) {
            int rbase = row0 + wr * WM + mt * 16 + (l4 << 2);
#pragma unroll
            for (int i = 0; i < 4; ++i) {
                int r = rbase + i;
                if (r < n && cok) {
                    float v = acc[mt][nt][i] + bv;
                    if (Cf) Cf[(size_t)r * outc + col] = v;
                    else Cbf[(size_t)r * outc + col] = f2bf(v);
                    ls += v;
                    lq += v * v;
                }
            }
        }
        if (st0 && cok) {
            int lc = wcc * WN + nt * 16 + l15;
            atomicAdd(&colred[0][lc], ls);
            atomicAdd(&colred[1][lc], lq);
        }
    }
    if (st0) {
        __syncthreads();
        for (int c = t; c < BN; c += 256) {
            if (col0 + c < outc) {
                atomicAdd(&st0[col0 + c], colred[0][c]);
                atomicAdd(&st1[col0 + c], colred[1][c]);
            }
        }
    }
}

// ---------------- BatchNorm ----------------

__global__ void bn_stats(const us* __restrict__ H, int n, int c,
                         float* __restrict__ s0, float* __restrict__ s1) {
    int col = threadIdx.x;
    if (col >= c) return;
    float s = 0.f, q = 0.f;
    for (int r = blockIdx.x; r < n; r += gridDim.x) {
        float v = bf2f(H[(size_t)r * c + col]);
        s += v;
        q += v * v;
    }
    atomicAdd(&s0[col], s);
    atomicAdd(&s1[col], q);
}

// bn_apply with inline finalize: scale/shift computed per block from s0/s1/g/be.
__global__ void bn_apply(us* __restrict__ H, int n8, int c,
                         const float* __restrict__ s0, const float* __restrict__ s1,
                         const float* __restrict__ g, const float* __restrict__ be, float fn) {
    __shared__ float sc[256], sh[256];
    int t = threadIdx.x;
    if (t < c) {
        float mean = s0[t] / fn;
        float var = s1[t] / fn - mean * mean;
        float s = g[t] * rsqrtf(var + 1e-5f);
        sc[t] = s;
        sh[t] = be[t] - mean * s;
    }
    __syncthreads();
    int cdiv8 = c >> 3;
    for (int i = blockIdx.x * blockDim.x + t; i < n8; i += gridDim.x * blockDim.x) {
        int col = (i % cdiv8) << 3;
        uint4 v = ((const uint4*)H)[i];
        float f[8];
        f[0] = __uint_as_float(v.x << 16); f[1] = __uint_as_float(v.x & 0xffff0000u);
        f[2] = __uint_as_float(v.y << 16); f[3] = __uint_as_float(v.y & 0xffff0000u);
        f[4] = __uint_as_float(v.z << 16); f[5] = __uint_as_float(v.z & 0xffff0000u);
        f[6] = __uint_as_float(v.w << 16); f[7] = __uint_as_float(v.w & 0xffff0000u);
        float4 sc0 = *(const float4*)&sc[col];
        float4 sc1 = *(const float4*)&sc[col + 4];
        float4 sh0 = *(const float4*)&sh[col];
        float4 sh1 = *(const float4*)&sh[col + 4];
        f[0] = fmaxf(f[0] * sc0.x + sh0.x, 0.f);
        f[1] = fmaxf(f[1] * sc0.y + sh0.y, 0.f);
        f[2] = fmaxf(f[2] * sc0.z + sh0.z, 0.f);
        f[3] = fmaxf(f[3] * sc0.w + sh0.w, 0.f);
        f[4] = fmaxf(f[4] * sc1.x + sh1.x, 0.f);
        f[5] = fmaxf(f[5] * sc1.y + sh1.y, 0.f);
        f[6] = fmaxf(f[6] * sc1.z + sh1.z, 0.f);
        f[7] = fmaxf(f[7] * sc1.w + sh1.w, 0.f);
        uint4 o;
        o.x = (unsigned)f2bf(f[0]) | ((unsigned)f2bf(f[1]) << 16);
        o.y = (unsigned)f2bf(f[2]) | ((unsigned)f2bf(f[3]) << 16);
        o.z = (unsigned)f2bf(f[4]) | ((unsigned)f2bf(f[5]) << 16);
        o.w = (unsigned)f2bf(f[6]) | ((unsigned)f2bf(f[7]) << 16);
        ((uint4*)H)[i] = o;
    }
}

// ---------------- host ----------------

extern "C" void kernel_launch(void* const* d_in, const int* in_sizes, int n_in,
                              void* d_out, int out_size, void* d_ws, size_t ws_size,
                              hipStream_t stream) {
    const float* x = (const float*)d_in[0];
    const int* ei = (const int*)d_in[1];
    const float* w1_l = (const float*)d_in[2];
    const float* b1_l = (const float*)d_in[3];
    const float* w1_r = (const float*)d_in[4];
    const float* g1 = (const float*)d_in[5];
    const float* be1 = (const float*)d_in[6];
    const float* w2_l = (const float*)d_in[7];
    const float* b2_l = (const float*)d_in[8];
    const float* w2_r = (const float*)d_in[9];
    const float* g2 = (const float*)d_in[10];
    const float* be2 = (const float*)d_in[11];
    const float* w3_l = (const float*)d_in[12];
    const float* b3_l = (const float*)d_in[13];
    const float* w3_r = (const float*)d_in[14];
    const float* g3 = (const float*)d_in[15];
    const float* be3 = (const float*)d_in[16];
    const float* wcf = (const float*)d_in[17];
    const float* bc = (const float*)d_in[18];

    const int N = in_sizes[0] / 128;
    const int E = in_sizes[1] / 2;
    const int NB = (N + 511) >> 9;
    const int G = 256;
    const int chunk = (E + G - 1) / G;

    char* ws = (char*)d_ws;
    size_t off = 0;
    auto alloc = [&](size_t bytes) -> char* {
        char* p = ws + off;
        off += (bytes + 255) & ~(size_t)255;
        return p;
    };
    int* rp = (int*)alloc((size_t)(N + 1) * 4);
    int* csr = (int*)alloc((size_t)E * 4);
    int* hist2 = (int*)alloc((size_t)G * NB * 4);
    int* bucketBase = (int*)alloc((size_t)(NB + 1) * 4);
    uint2* ebuf = (uint2*)alloc((size_t)E * 8);
    us* xbf = (us*)alloc((size_t)N * 128 * 2);
    us* M = (us*)alloc((size_t)N * 256 * 2);   // gather out / Yc
    us* Ha = (us*)alloc((size_t)N * 256 * 2);  // h1 raw -> relu(bn1(h1)); later h3
    us* Hb = (us*)alloc((size_t)N * 256 * 2);  // h2 raw -> relu(bn2(h2))
    float* stats = (float*)alloc(6 * 256 * 4); // s0_1 s1_1 s0_2 s1_2 s0_3 s1_3
    float* s01 = stats, *s11 = stats + 256;
    float* s02 = stats + 512, *s12 = stats + 768;
    float* s03 = stats + 1024, *s13 = stats + 1280;
    us* wcat1 = (us*)alloc(256 * 256 * 2);     // [256][128+128] = [w1_l | w1_r]
    us* wcat2 = (us*)alloc(256 * 512 * 2);     // [256][256+256] = [w2_l | w2_r]
    us* w3cat = (us*)alloc(256 * 256 * 2);     // rows 0-127 w3_l, 128-255 w3_r
    us* wc_b = (us*)alloc(16 * 128 * 2);
    alloc(1 << 20);                             // pad: absorbs OOB staging reads
    (void)ws_size; (void)n_in; (void)out_size;

    // --- conversions + CSR build + stat zero ---
    hipMemsetAsync(stats, 0, 6 * 256 * 4, stream);
    WConvAll wc;
    wc.seg[0] = {x,    xbf,         N * 128 / 4,  5, 128};
    wc.seg[1] = {w1_l, wcat1,       256 * 128 / 4, 5, 256};
    wc.seg[2] = {w1_r, wcat1 + 128, 256 * 128 / 4, 5, 256};
    wc.seg[3] = {w2_l, wcat2,       256 * 256 / 4, 6, 512};
    wc.seg[4] = {w2_r, wcat2 + 256, 256 * 256 / 4, 6, 512};
    wc.seg[5] = {w3_l, w3cat,             128 * 256 / 4, 6, 256};
    wc.seg[6] = {w3_r, w3cat + 128 * 256, 128 * 256 / 4, 6, 256};
    wc.seg[7] = {wcf,  wc_b,        15 * 128 / 4,  5, 128};
    conv_all<<<1024, 256, 0, stream>>>(wc);
    bucket_hist<<<G, 256, 0, stream>>>(ei, E, hist2, NB, chunk);
    bucket_offsets<<<1, 256, 0, stream>>>(hist2, bucketBase, rp, N, G, NB);
    scatter8<<<G, 256, 0, stream>>>(ei, E, hist2, ebuf, NB, chunk);
    fine_csr<<<NB, 256, 0, stream>>>(ebuf, bucketBase, N, rp, csr);

    const int aggGrid = (N + 3) / 4;
    const int rowTiles = (N + 127) / 128;

    // --- layer 1: 128 -> 256 (stats fused into GEMM) ---
    agg_mean<2><<<aggGrid, 256, 0, stream>>>(xbf, rp, csr, M, N);
    gemm_mfma<128, 128, 64, 64><<<dim3(rowTiles, 2), 256, 0, stream>>>(
        M, 128, xbf, 128, wcat1, b1_l, N, 256, Ha, nullptr, s01, s11);
    bn_apply<<<2048, 256, 0, stream>>>(Ha, N * 256 / 8, 256, s01, s11, g1, be1, (float)N);

    // --- layer 2: 256 -> 256 (stats fused into GEMM) ---
    agg_mean<4><<<aggGrid, 256, 0, stream>>>(Ha, rp, csr, M, N);
    gemm_mfma<128, 128, 64, 64><<<dim3(rowTiles, 2), 256, 0, stream>>>(
        M, 256, Ha, 256, wcat2, b2_l, N, 256, Hb, nullptr, s02, s12);
    bn_apply<<<2048, 256, 0, stream>>>(Hb, N * 256 / 8, 256, s02, s12, g2, be2, (float)N);

    // --- layer 3: GEMM-first: [Y|Z] = Hb @ [w3l;w3r]^T, aggregate 128 cols ---
    gemm_mfma<128, 128, 64, 64><<<dim3(rowTiles, 2), 256, 0, stream>>>(
        Hb, 256, nullptr, 0, w3cat, nullptr, N, 256, M, nullptr, nullptr, nullptr);
    agg_post<<<aggGrid, 256, 0, stream>>>(M, rp, csr, b3_l, Ha, N);
    bn_stats<<<1024, 256, 0, stream>>>(Ha, N, 128, s03, s13);
    bn_apply<<<2048, 256, 0, stream>>>(Ha, N * 128 / 8, 128, s03, s13, g3, be3, (float)N);

    // --- classifier: 128 -> 15 (f32 out) ---
    gemm_mfma<128, 16, 32, 16><<<dim3(rowTiles, 1), 256, 0, stream>>>(
        Ha, 128, nullptr, 0, wc_b, bc, N, 15, nullptr, (float*)d_out, nullptr, nullptr);
}

// Round 8
// 847.723 us; speedup vs baseline: 1.3926x; 1.0726x over previous
//
#include <hip/hip_runtime.h>

// GraphSAGE 3-layer + BN(train stats) + ReLU + classifier, MI355X.
// R8: GEMM K-loop software-pipelined AITER-style: double LDS buffers,
//     distance-2 global_load_lds prefetch, manual `s_waitcnt vmcnt(NDMA)`
//     (never 0 mid-loop) + raw `s_barrier` asm (compiler's __syncthreads
//     would force vmcnt(0) and drain the prefetch). 8-way replicated BN
//     stat accumulators kill cross-XCD atomic line contention.

#define DEV static __device__ __forceinline__

typedef unsigned short us;
typedef __attribute__((ext_vector_type(8))) __bf16 bf16x8;
typedef __attribute__((ext_vector_type(4))) float f32x4;

DEV float bf2f(us u) { return __uint_as_float(((unsigned)u) << 16); }
DEV us f2bf(float f) {
    unsigned u = __float_as_uint(f);
    unsigned r = u + 0x7fffu + ((u >> 16) & 1u);  // round-nearest-even
    return (us)(r >> 16);
}

typedef __attribute__((address_space(3))) void lds_void;
typedef const __attribute__((address_space(1))) void gbl_void;
DEV void gll16(const void* g, void* l) {
    __builtin_amdgcn_global_load_lds((gbl_void*)g, (lds_void*)l, 16, 0, 0);
}

DEV bool is_i64(const int* ei) {
    return (ei[1] == 0) & (ei[3] == 0) & (ei[5] == 0) & (ei[7] == 0);
}

// ---------------- CSR build (bucketed two-level) ----------------

__global__ void bucket_hist(const int* __restrict__ ei, int E, int* __restrict__ hist2,
                            int NB, int chunk) {
    __shared__ int h[256];
    const int g = blockIdx.x, t = threadIdx.x;
    const bool i64 = is_i64(ei);
    h[t] = 0;
    __syncthreads();
    int beg = g * chunk, end = min(beg + chunk, E);
    for (int e = beg + t; e < end; e += 256) {
        int d = i64 ? ei[2 * (E + e)] : ei[E + e];
        atomicAdd(&h[d >> 9], 1);
    }
    __syncthreads();
    if (t < NB) hist2[g * NB + t] = h[t];
}

__global__ void bucket_offsets(int* __restrict__ hist2, int* __restrict__ bucketBase,
                               int* __restrict__ rp, int N, int G, int NB) {
    __shared__ int tot[256];
    const int t = threadIdx.x;
    int sum = 0;
    if (t < NB)
        for (int g = 0; g < G; ++g) sum += hist2[g * NB + t];
    tot[t] = sum;
    __syncthreads();
    for (int off = 1; off < 256; off <<= 1) {
        int v = (t >= off) ? tot[t - off] : 0;
        __syncthreads();
        tot[t] += v;
        __syncthreads();
    }
    int base = tot[t] - sum;
    if (t < NB) {
        bucketBase[t] = base;
        int run = base;
        for (int g = 0; g < G; ++g) {
            int v = hist2[g * NB + t];
            hist2[g * NB + t] = run;
            run += v;
        }
        if (t == NB - 1) {
            bucketBase[NB] = tot[t];
            rp[N] = tot[t];
        }
    }
}

__global__ void scatter8(const int* __restrict__ ei, int E, const int* __restrict__ hist2,
                         uint2* __restrict__ ebuf, int NB, int chunk) {
    __shared__ int off[256];
    const int g = blockIdx.x, t = threadIdx.x;
    const bool i64 = is_i64(ei);
    if (t < NB) off[t] = hist2[g * NB + t];
    __syncthreads();
    int beg = g * chunk, end = min(beg + chunk, E);
    for (int e = beg + t; e < end; e += 256) {
        int s = i64 ? ei[2 * e] : ei[e];
        int d = i64 ? ei[2 * (E + e)] : ei[E + e];
        int p = atomicAdd(&off[d >> 9], 1);
        ebuf[p] = make_uint2((unsigned)s, (unsigned)d);
    }
}

__global__ void fine_csr(const uint2* __restrict__ ebuf, const int* __restrict__ bucketBase,
                         int N, int* __restrict__ rp, int* __restrict__ csr) {
    __shared__ int cnt[512];
    __shared__ int red[256];
    const int b = blockIdx.x, t = threadIdx.x;
    const int node0 = b << 9;
    cnt[t] = 0;
    cnt[t + 256] = 0;
    __syncthreads();
    const int ebeg = bucketBase[b], eend = bucketBase[b + 1];
    for (int e = ebeg + t; e < eend; e += 256) {
        uint2 r = ebuf[e];
        atomicAdd(&cnt[r.y & 511], 1);
    }
    __syncthreads();
    int c0 = cnt[2 * t], c1 = cnt[2 * t + 1];
    int s = c0 + c1;
    red[t] = s;
    __syncthreads();
    for (int off = 1; off < 256; off <<= 1) {
        int v = (t >= off) ? red[t - off] : 0;
        __syncthreads();
        red[t] += v;
        __syncthreads();
    }
    int pre = red[t] - s;
    int n0 = node0 + 2 * t;
    if (n0 < N) rp[n0] = ebeg + pre;
    if (n0 + 1 < N) rp[n0 + 1] = ebeg + pre + c0;
    __syncthreads();
    cnt[2 * t] = ebeg + pre;
    cnt[2 * t + 1] = ebeg + pre + c0;
    __syncthreads();
    for (int e = ebeg + t; e < eend; e += 256) {
        uint2 r = ebuf[e];
        int p = atomicAdd(&cnt[r.y & 511], 1);
        csr[p] = (int)r.x;
    }
}

// ---------------- f32 -> bf16 conversion (x + all weights, one kernel) ----

struct WSeg { const float* s; us* d; int n4; int l2w4; int stride; };
struct WConvAll { WSeg seg[8]; };

__global__ void conv_all(WConvAll wc) {
    for (int sg = 0; sg < 8; ++sg) {
        WSeg w = wc.seg[sg];
        for (int i = blockIdx.x * blockDim.x + threadIdx.x; i < w.n4; i += gridDim.x * blockDim.x) {
            float4 v = ((const float4*)w.s)[i];
            ushort4 r;
            r.x = f2bf(v.x); r.y = f2bf(v.y); r.z = f2bf(v.z); r.w = f2bf(v.w);
            int row = i >> w.l2w4;
            int col = (i - (row << w.l2w4)) * 4;
            *(ushort4*)(w.d + (size_t)row * w.stride + col) = r;
        }
    }
}

// ---------------- mean aggregation (wave per node, unroll-4) ----------------

template <int VEC>  // cols = 64*VEC
__global__ void agg_mean(const us* __restrict__ X, const int* __restrict__ rp,
                         const int* __restrict__ csr, us* __restrict__ M, int n) {
    const int cols = VEC * 64;
    int w = blockIdx.x * (blockDim.x >> 6) + (threadIdx.x >> 6);
    int lane = threadIdx.x & 63;
    if (w >= n) return;
    int beg = rp[w], end = rp[w + 1];
    const us* Xb = X + lane * VEC;
    float acc[VEC];
#pragma unroll
    for (int i = 0; i < VEC; ++i) acc[i] = 0.f;
    int e = beg;
    for (; e + 4 <= end; e += 4) {
        int j0 = csr[e], j1 = csr[e + 1], j2 = csr[e + 2], j3 = csr[e + 3];
        if (VEC == 2) {
            unsigned u0 = *(const unsigned*)(Xb + (size_t)j0 * cols);
            unsigned u1 = *(const unsigned*)(Xb + (size_t)j1 * cols);
            unsigned u2 = *(const unsigned*)(Xb + (size_t)j2 * cols);
            unsigned u3 = *(const unsigned*)(Xb + (size_t)j3 * cols);
            acc[0] += __uint_as_float(u0 << 16) + __uint_as_float(u1 << 16)
                    + __uint_as_float(u2 << 16) + __uint_as_float(u3 << 16);
            acc[1] += __uint_as_float(u0 & 0xffff0000u) + __uint_as_float(u1 & 0xffff0000u)
                    + __uint_as_float(u2 & 0xffff0000u) + __uint_as_float(u3 & 0xffff0000u);
        } else {
            uint2 u0 = *(const uint2*)(Xb + (size_t)j0 * cols);
            uint2 u1 = *(const uint2*)(Xb + (size_t)j1 * cols);
            uint2 u2 = *(const uint2*)(Xb + (size_t)j2 * cols);
            uint2 u3 = *(const uint2*)(Xb + (size_t)j3 * cols);
            acc[0] += __uint_as_float(u0.x << 16) + __uint_as_float(u1.x << 16)
                    + __uint_as_float(u2.x << 16) + __uint_as_float(u3.x << 16);
            acc[1] += __uint_as_float(u0.x & 0xffff0000u) + __uint_as_float(u1.x & 0xffff0000u)
                    + __uint_as_float(u2.x & 0xffff0000u) + __uint_as_float(u3.x & 0xffff0000u);
            acc[2] += __uint_as_float(u0.y << 16) + __uint_as_float(u1.y << 16)
                    + __uint_as_float(u2.y << 16) + __uint_as_float(u3.y << 16);
            acc[3] += __uint_as_float(u0.y & 0xffff0000u) + __uint_as_float(u1.y & 0xffff0000u)
                    + __uint_as_float(u2.y & 0xffff0000u) + __uint_as_float(u3.y & 0xffff0000u);
        }
    }
    for (; e < end; ++e) {
        int j0 = csr[e];
        if (VEC == 2) {
            unsigned u0 = *(const unsigned*)(Xb + (size_t)j0 * cols);
            acc[0] += __uint_as_float(u0 << 16);
            acc[1] += __uint_as_float(u0 & 0xffff0000u);
        } else {
            uint2 u0 = *(const uint2*)(Xb + (size_t)j0 * cols);
            acc[0] += __uint_as_float(u0.x << 16);
            acc[1] += __uint_as_float(u0.x & 0xffff0000u);
            acc[2] += __uint_as_float(u0.y << 16);
            acc[3] += __uint_as_float(u0.y & 0xffff0000u);
        }
    }
    float inv = 1.0f / (float)max(end - beg, 1);
    us* q = M + (size_t)w * cols + lane * VEC;
    if (VEC == 2) {
        *(ushort2*)q = make_ushort2(f2bf(acc[0] * inv), f2bf(acc[1] * inv));
    } else {
        *(ushort4*)q = make_ushort4(f2bf(acc[0] * inv), f2bf(acc[1] * inv),
                                    f2bf(acc[2] * inv), f2bf(acc[3] * inv));
    }
}

// layer-3 post-GEMM aggregation (unroll-4)
__global__ void agg_post(const us* __restrict__ Yc, const int* __restrict__ rp,
                         const int* __restrict__ csr, const float* __restrict__ bias,
                         us* __restrict__ H, int n) {
    int w = blockIdx.x * (blockDim.x >> 6) + (threadIdx.x >> 6);
    int lane = threadIdx.x & 63;
    if (w >= n) return;
    int beg = rp[w], end = rp[w + 1];
    const us* Yb = Yc + lane * 2;
    float a0 = 0.f, a1 = 0.f;
    int e = beg;
    for (; e + 4 <= end; e += 4) {
        int j0 = csr[e], j1 = csr[e + 1], j2 = csr[e + 2], j3 = csr[e + 3];
        unsigned u0 = *(const unsigned*)(Yb + (size_t)j0 * 256);
        unsigned u1 = *(const unsigned*)(Yb + (size_t)j1 * 256);
        unsigned u2 = *(const unsigned*)(Yb + (size_t)j2 * 256);
        unsigned u3 = *(const unsigned*)(Yb + (size_t)j3 * 256);
        a0 += __uint_as_float(u0 << 16) + __uint_as_float(u1 << 16)
            + __uint_as_float(u2 << 16) + __uint_as_float(u3 << 16);
        a1 += __uint_as_float(u0 & 0xffff0000u) + __uint_as_float(u1 & 0xffff0000u)
            + __uint_as_float(u2 & 0xffff0000u) + __uint_as_float(u3 & 0xffff0000u);
    }
    for (; e < end; ++e) {
        unsigned u0 = *(const unsigned*)(Yb + (size_t)csr[e] * 256);
        a0 += __uint_as_float(u0 << 16);
        a1 += __uint_as_float(u0 & 0xffff0000u);
    }
    float inv = 1.0f / (float)max(end - beg, 1);
    unsigned uz = *(const unsigned*)(Yc + (size_t)w * 256 + 128 + lane * 2);
    float2 bv = *(const float2*)(bias + lane * 2);
    float r0 = a0 * inv + __uint_as_float(uz << 16) + bv.x;
    float r1 = a1 * inv + __uint_as_float(uz & 0xffff0000u) + bv.y;
    *(ushort2*)(H + (size_t)w * 128 + lane * 2) = make_ushort2(f2bf(r0), f2bf(r1));
}

// ---------------- MFMA GEMM: distance-2 DMA pipeline, dual LDS buffers ----
// C = [A0|A1] @ W^T + bias; optional replicated BN-stats accumulation.

template <int BM, int BN, int WM, int WN>
__launch_bounds__(256)
__global__ void gemm_mfma(const us* __restrict__ A0, int K0,
                          const us* __restrict__ A1, int K1,
                          const us* __restrict__ W, const float* __restrict__ bias,
                          int n, int outc, us* __restrict__ Cbf, float* __restrict__ Cf,
                          float* __restrict__ st0, float* __restrict__ st1) {
    constexpr int MT = WM / 16;
    constexpr int NT = WN / 16;
    constexpr int WCols = BN / WN;
    constexpr int NDMA = (BM * 4 + BN * 4) / 256;  // DMA instrs per wave per tile
    static_assert((BM * 4) % 256 == 0 && (BN * 4) % 256 == 0, "uniform DMA count");
    static_assert((BM / WM) * (BN / WN) == 4, "4 waves");
    __shared__ __align__(16) us As[2][BM * 32];
    __shared__ __align__(16) us Bs[2][BN * 32];
    __shared__ float colred[2][BN];

    const int t = threadIdx.x;
    const int wid = t >> 6, lane = t & 63;
    const int wr = wid / WCols, wcc = wid % WCols;
    const int row0 = blockIdx.x * BM;
    const int col0 = blockIdx.y * BN;
    const int Kp = K0 + K1;
    const int nk = Kp >> 5;
    const int l15 = lane & 15, l4 = lane >> 4;

    auto issue = [&](int kidx, int p) {
        int kc = kidx << 5;
        const us* A = (kc < K0) ? A0 : A1;
        int rs = (kc < K0) ? K0 : K1;
        int ko = (kc < K0) ? kc : kc - K0;
#pragma unroll
        for (int c = t; c < BM * 4; c += 256) {
            int blk = c >> 6;
            int row = row0 + (blk << 4) + l15;
            gll16(A + (size_t)row * rs + ko + (l4 << 3), (char*)As[p] + blk * 1024 + lane * 16);
        }
#pragma unroll
        for (int c = t; c < BN * 4; c += 256) {
            int blk = c >> 6;
            int col = col0 + (blk << 4) + l15;
            gll16(W + (size_t)col * Kp + kc + (l4 << 3), (char*)Bs[p] + blk * 1024 + lane * 16);
        }
    };

    f32x4 acc[MT][NT];
#pragma unroll
    for (int i = 0; i < MT; ++i)
#pragma unroll
        for (int j = 0; j < NT; ++j) acc[i][j] = (f32x4){0.f, 0.f, 0.f, 0.f};

    issue(0, 0);
    if (nk > 1) issue(1, 1);
    for (int k = 0; k < nk; ++k) {
        // retire tile k's DMAs only; tile k+1 stays in flight (never vmcnt(0) mid-loop)
        if (k + 1 < nk) asm volatile("s_waitcnt vmcnt(%0)" :: "i"(NDMA) : "memory");
        else            asm volatile("s_waitcnt vmcnt(0)" ::: "memory");
        asm volatile("s_barrier" ::: "memory");
        const int p = k & 1;
        bf16x8 af[MT], bfr[NT];
#pragma unroll
        for (int mt = 0; mt < MT; ++mt)
            af[mt] = *(const bf16x8*)((char*)As[p] + (wr * MT + mt) * 1024 + lane * 16);
#pragma unroll
        for (int nt = 0; nt < NT; ++nt)
            bfr[nt] = *(const bf16x8*)((char*)Bs[p] + (wcc * NT + nt) * 1024 + lane * 16);
#pragma unroll
        for (int mt = 0; mt < MT; ++mt)
#pragma unroll
            for (int nt = 0; nt < NT; ++nt)
                acc[mt][nt] = __builtin_amdgcn_mfma_f32_16x16x32_bf16(af[mt], bfr[nt], acc[mt][nt], 0, 0, 0);
        if (k + 2 < nk) {
            asm volatile("s_barrier" ::: "memory");  // all waves done reading buf p
            issue(k + 2, p);
        }
    }

    if (st0) {
#pragma unroll
        for (int c = t; c < 2 * BN; c += 256) (&colred[0][0])[c] = 0.f;
        __syncthreads();
    }

    // epilogue: C/D map col=lane&15, row=(lane>>4)*4+reg
#pragma unroll
    for (int nt = 0; nt < NT; ++nt) {
        int col = col0 + wcc * WN + nt * 16 + l15;
        bool cok = col < outc;
        float bv = (bias != nullptr && cok) ? bias[col] : 0.f;
        float ls = 0.f, lq = 0.f;
#pragma unroll
        for (int mt = 0; mt < MT; ++mt) {
            int rbase = row0 + wr * WM + mt * 16 + (l4 << 2);
#pragma unroll
            for (int i = 0; i < 4; ++i) {
                int r = rbase + i;
                if (r < n && cok) {
                    float v = acc[mt][nt][i] + bv;
                    if (Cf) Cf[(size_t)r * outc + col] = v;
                    else Cbf[(size_t)r * outc + col] = f2bf(v);
                    ls += v;
                    lq += v * v;
                }
            }
        }
        if (st0 && cok) {
            int lc = wcc * WN + nt * 16 + l15;
            atomicAdd(&colred[0][lc], ls);
            atomicAdd(&colred[1][lc], lq);
        }
    }
    if (st0) {
        __syncthreads();
        int rep = (blockIdx.x & 7) << 8;  // 8-way replicated accumulators
        for (int c = t; c < BN; c += 256) {
            if (col0 + c < outc) {
                atomicAdd(&st0[rep + col0 + c], colred[0][c]);
                atomicAdd(&st1[rep + col0 + c], colred[1][c]);
            }
        }
    }
}

// ---------------- BatchNorm ----------------

__global__ void bn_stats(const us* __restrict__ H, int n, int c,
                         float* __restrict__ s0, float* __restrict__ s1) {
    int col = threadIdx.x;
    if (col >= c) return;
    float s = 0.f, q = 0.f;
    for (int r = blockIdx.x; r < n; r += gridDim.x) {
        float v = bf2f(H[(size_t)r * c + col]);
        s += v;
        q += v * v;
    }
    int rep = (blockIdx.x & 7) << 8;
    atomicAdd(&s0[rep + col], s);
    atomicAdd(&s1[rep + col], q);
}

// bn_apply with inline finalize (sums 8 stat replicas).
__global__ void bn_apply(us* __restrict__ H, int n8, int c,
                         const float* __restrict__ s0, const float* __restrict__ s1,
                         const float* __restrict__ g, const float* __restrict__ be, float fn) {
    __shared__ float sc[256], sh[256];
    int t = threadIdx.x;
    if (t < c) {
        float s = 0.f, q = 0.f;
#pragma unroll
        for (int r = 0; r < 8; ++r) {
            s += s0[(r << 8) + t];
            q += s1[(r << 8) + t];
        }
        float mean = s / fn;
        float var = q / fn - mean * mean;
        float scale = g[t] * rsqrtf(var + 1e-5f);
        sc[t] = scale;
        sh[t] = be[t] - mean * scale;
    }
    __syncthreads();
    int cdiv8 = c >> 3;
    for (int i = blockIdx.x * blockDim.x + t; i < n8; i += gridDim.x * blockDim.x) {
        int col = (i % cdiv8) << 3;
        uint4 v = ((const uint4*)H)[i];
        float f[8];
        f[0] = __uint_as_float(v.x << 16); f[1] = __uint_as_float(v.x & 0xffff0000u);
        f[2] = __uint_as_float(v.y << 16); f[3] = __uint_as_float(v.y & 0xffff0000u);
        f[4] = __uint_as_float(v.z << 16); f[5] = __uint_as_float(v.z & 0xffff0000u);
        f[6] = __uint_as_float(v.w << 16); f[7] = __uint_as_float(v.w & 0xffff0000u);
        float4 sc0 = *(const float4*)&sc[col];
        float4 sc1 = *(const float4*)&sc[col + 4];
        float4 sh0 = *(const float4*)&sh[col];
        float4 sh1 = *(const float4*)&sh[col + 4];
        f[0] = fmaxf(f[0] * sc0.x + sh0.x, 0.f);
        f[1] = fmaxf(f[1] * sc0.y + sh0.y, 0.f);
        f[2] = fmaxf(f[2] * sc0.z + sh0.z, 0.f);
        f[3] = fmaxf(f[3] * sc0.w + sh0.w, 0.f);
        f[4] = fmaxf(f[4] * sc1.x + sh1.x, 0.f);
        f[5] = fmaxf(f[5] * sc1.y + sh1.y, 0.f);
        f[6] = fmaxf(f[6] * sc1.z + sh1.z, 0.f);
        f[7] = fmaxf(f[7] * sc1.w + sh1.w, 0.f);
        uint4 o;
        o.x = (unsigned)f2bf(f[0]) | ((unsigned)f2bf(f[1]) << 16);
        o.y = (unsigned)f2bf(f[2]) | ((unsigned)f2bf(f[3]) << 16);
        o.z = (unsigned)f2bf(f[4]) | ((unsigned)f2bf(f[5]) << 16);
        o.w = (unsigned)f2bf(f[6]) | ((unsigned)f2bf(f[7]) << 16);
        ((uint4*)H)[i] = o;
    }
}

// ---------------- host ----------------

extern "C" void kernel_launch(void* const* d_in, const int* in_sizes, int n_in,
                              void* d_out, int out_size, void* d_ws, size_t ws_size,
                              hipStream_t stream) {
    const float* x = (const float*)d_in[0];
    const int* ei = (const int*)d_in[1];
    const float* w1_l = (const float*)d_in[2];
    const float* b1_l = (const float*)d_in[3];
    const float* w1_r = (const float*)d_in[4];
    const float* g1 = (const float*)d_in[5];
    const float* be1 = (const float*)d_in[6];
    const float* w2_l = (const float*)d_in[7];
    const float* b2_l = (const float*)d_in[8];
    const float* w2_r = (const float*)d_in[9];
    const float* g2 = (const float*)d_in[10];
    const float* be2 = (const float*)d_in[11];
    const float* w3_l = (const float*)d_in[12];
    const float* b3_l = (const float*)d_in[13];
    const float* w3_r = (const float*)d_in[14];
    const float* g3 = (const float*)d_in[15];
    const float* be3 = (const float*)d_in[16];
    const float* wcf = (const float*)d_in[17];
    const float* bc = (const float*)d_in[18];

    const int N = in_sizes[0] / 128;
    const int E = in_sizes[1] / 2;
    const int NB = (N + 511) >> 9;
    const int G = 256;
    const int chunk = (E + G - 1) / G;

    char* ws = (char*)d_ws;
    size_t off = 0;
    auto alloc = [&](size_t bytes) -> char* {
        char* p = ws + off;
        off += (bytes + 255) & ~(size_t)255;
        return p;
    };
    int* rp = (int*)alloc((size_t)(N + 1) * 4);
    int* csr = (int*)alloc((size_t)E * 4);
    int* hist2 = (int*)alloc((size_t)G * NB * 4);
    int* bucketBase = (int*)alloc((size_t)(NB + 1) * 4);
    uint2* ebuf = (uint2*)alloc((size_t)E * 8);
    us* xbf = (us*)alloc((size_t)N * 128 * 2);
    us* M = (us*)alloc((size_t)N * 256 * 2);   // gather out / Yc
    us* Ha = (us*)alloc((size_t)N * 256 * 2);  // h1; later h3
    us* Hb = (us*)alloc((size_t)N * 256 * 2);  // h2
    // 8-replica stats: per layer s0[8*256], s1[8*256]
    float* stats = (float*)alloc(6 * 8 * 256 * 4);
    float* s01 = stats,          *s11 = stats + 2048;
    float* s02 = stats + 4096,   *s12 = stats + 6144;
    float* s03 = stats + 8192,   *s13 = stats + 10240;
    us* wcat1 = (us*)alloc(256 * 256 * 2);     // [256][128+128] = [w1_l | w1_r]
    us* wcat2 = (us*)alloc(256 * 512 * 2);     // [256][256+256] = [w2_l | w2_r]
    us* w3cat = (us*)alloc(256 * 256 * 2);     // rows 0-127 w3_l, 128-255 w3_r
    us* wc_b = (us*)alloc(64 * 128 * 2);       // 64 rows (rows 15-63 masked)
    alloc(1 << 20);                             // pad: absorbs OOB staging reads
    (void)ws_size; (void)n_in; (void)out_size;

    // --- conversions + CSR build + stat zero ---
    hipMemsetAsync(stats, 0, 6 * 8 * 256 * 4, stream);
    WConvAll wc;
    wc.seg[0] = {x,    xbf,         N * 128 / 4,  5, 128};
    wc.seg[1] = {w1_l, wcat1,       256 * 128 / 4, 5, 256};
    wc.seg[2] = {w1_r, wcat1 + 128, 256 * 128 / 4, 5, 256};
    wc.seg[3] = {w2_l, wcat2,       256 * 256 / 4, 6, 512};
    wc.seg[4] = {w2_r, wcat2 + 256, 256 * 256 / 4, 6, 512};
    wc.seg[5] = {w3_l, w3cat,             128 * 256 / 4, 6, 256};
    wc.seg[6] = {w3_r, w3cat + 128 * 256, 128 * 256 / 4, 6, 256};
    wc.seg[7] = {wcf,  wc_b,        15 * 128 / 4,  5, 128};
    conv_all<<<1024, 256, 0, stream>>>(wc);
    bucket_hist<<<G, 256, 0, stream>>>(ei, E, hist2, NB, chunk);
    bucket_offsets<<<1, 256, 0, stream>>>(hist2, bucketBase, rp, N, G, NB);
    scatter8<<<G, 256, 0, stream>>>(ei, E, hist2, ebuf, NB, chunk);
    fine_csr<<<NB, 256, 0, stream>>>(ebuf, bucketBase, N, rp, csr);

    const int aggGrid = (N + 3) / 4;
    const int rowTiles = (N + 127) / 128;

    // --- layer 1: 128 -> 256 (stats fused) ---
    agg_mean<2><<<aggGrid, 256, 0, stream>>>(xbf, rp, csr, M, N);
    gemm_mfma<128, 128, 64, 64><<<dim3(rowTiles, 2), 256, 0, stream>>>(
        M, 128, xbf, 128, wcat1, b1_l, N, 256, Ha, nullptr, s01, s11);
    bn_apply<<<2048, 256, 0, stream>>>(Ha, N * 256 / 8, 256, s01, s11, g1, be1, (float)N);

    // --- layer 2: 256 -> 256 (stats fused) ---
    agg_mean<4><<<aggGrid, 256, 0, stream>>>(Ha, rp, csr, M, N);
    gemm_mfma<128, 128, 64, 64><<<dim3(rowTiles, 2), 256, 0, stream>>>(
        M, 256, Ha, 256, wcat2, b2_l, N, 256, Hb, nullptr, s02, s12);
    bn_apply<<<2048, 256, 0, stream>>>(Hb, N * 256 / 8, 256, s02, s12, g2, be2, (float)N);

    // --- layer 3: GEMM-first: [Y|Z] = Hb @ [w3l;w3r]^T, aggregate 128 cols ---
    gemm_mfma<128, 128, 64, 64><<<dim3(rowTiles, 2), 256, 0, stream>>>(
        Hb, 256, nullptr, 0, w3cat, nullptr, N, 256, M, nullptr, nullptr, nullptr);
    agg_post<<<aggGrid, 256, 0, stream>>>(M, rp, csr, b3_l, Ha, N);
    bn_stats<<<1024, 256, 0, stream>>>(Ha, N, 128, s03, s13);
    bn_apply<<<2048, 256, 0, stream>>>(Ha, N * 128 / 8, 128, s03, s13, g3, be3, (float)N);

    // --- classifier: 128 -> 15 (f32 out); BN=64 keeps DMA counts wave-uniform ---
    gemm_mfma<128, 64, 128, 16><<<dim3(rowTiles, 1), 256, 0, stream>>>(
        Ha, 128, nullptr, 0, wc_b, bc, N, 15, nullptr, (float*)d_out, nullptr, nullptr);
}

// Round 9
// 798.480 us; speedup vs baseline: 1.4785x; 1.0617x over previous
//
#include <hip/hip_runtime.h>

// GraphSAGE 3-layer + BN(train stats) + ReLU + classifier, MI355X.
// R9: GEMM widened to 512 threads / 8 waves of 64x64, BM=128 BN=256 single
//     col-block (A read ONCE, was twice), LDS dbuf 48KB -> 3 blocks/CU
//     (~75% occ). Distance-2 global_load_lds pipeline kept (NDMA=3,
//     vmcnt never 0 mid-loop, raw s_barrier). Gather/CSR/BN unchanged
//     (agg_mean is at its bytes ceiling per R8 analysis).

#define DEV static __device__ __forceinline__

typedef unsigned short us;
typedef __attribute__((ext_vector_type(8))) __bf16 bf16x8;
typedef __attribute__((ext_vector_type(4))) float f32x4;

DEV float bf2f(us u) { return __uint_as_float(((unsigned)u) << 16); }
DEV us f2bf(float f) {
    unsigned u = __float_as_uint(f);
    unsigned r = u + 0x7fffu + ((u >> 16) & 1u);  // round-nearest-even
    return (us)(r >> 16);
}

typedef __attribute__((address_space(3))) void lds_void;
typedef const __attribute__((address_space(1))) void gbl_void;
DEV void gll16(const void* g, void* l) {
    __builtin_amdgcn_global_load_lds((gbl_void*)g, (lds_void*)l, 16, 0, 0);
}

DEV bool is_i64(const int* ei) {
    return (ei[1] == 0) & (ei[3] == 0) & (ei[5] == 0) & (ei[7] == 0);
}

// ---------------- CSR build (bucketed two-level) ----------------

__global__ void bucket_hist(const int* __restrict__ ei, int E, int* __restrict__ hist2,
                            int NB, int chunk) {
    __shared__ int h[256];
    const int g = blockIdx.x, t = threadIdx.x;
    const bool i64 = is_i64(ei);
    h[t] = 0;
    __syncthreads();
    int beg = g * chunk, end = min(beg + chunk, E);
    for (int e = beg + t; e < end; e += 256) {
        int d = i64 ? ei[2 * (E + e)] : ei[E + e];
        atomicAdd(&h[d >> 9], 1);
    }
    __syncthreads();
    if (t < NB) hist2[g * NB + t] = h[t];
}

__global__ void bucket_offsets(int* __restrict__ hist2, int* __restrict__ bucketBase,
                               int* __restrict__ rp, int N, int G, int NB) {
    __shared__ int tot[256];
    const int t = threadIdx.x;
    int sum = 0;
    if (t < NB)
        for (int g = 0; g < G; ++g) sum += hist2[g * NB + t];
    tot[t] = sum;
    __syncthreads();
    for (int off = 1; off < 256; off <<= 1) {
        int v = (t >= off) ? tot[t - off] : 0;
        __syncthreads();
        tot[t] += v;
        __syncthreads();
    }
    int base = tot[t] - sum;
    if (t < NB) {
        bucketBase[t] = base;
        int run = base;
        for (int g = 0; g < G; ++g) {
            int v = hist2[g * NB + t];
            hist2[g * NB + t] = run;
            run += v;
        }
        if (t == NB - 1) {
            bucketBase[NB] = tot[t];
            rp[N] = tot[t];
        }
    }
}

__global__ void scatter8(const int* __restrict__ ei, int E, const int* __restrict__ hist2,
                         uint2* __restrict__ ebuf, int NB, int chunk) {
    __shared__ int off[256];
    const int g = blockIdx.x, t = threadIdx.x;
    const bool i64 = is_i64(ei);
    if (t < NB) off[t] = hist2[g * NB + t];
    __syncthreads();
    int beg = g * chunk, end = min(beg + chunk, E);
    for (int e = beg + t; e < end; e += 256) {
        int s = i64 ? ei[2 * e] : ei[e];
        int d = i64 ? ei[2 * (E + e)] : ei[E + e];
        int p = atomicAdd(&off[d >> 9], 1);
        ebuf[p] = make_uint2((unsigned)s, (unsigned)d);
    }
}

__global__ void fine_csr(const uint2* __restrict__ ebuf, const int* __restrict__ bucketBase,
                         int N, int* __restrict__ rp, int* __restrict__ csr) {
    __shared__ int cnt[512];
    __shared__ int red[256];
    const int b = blockIdx.x, t = threadIdx.x;
    const int node0 = b << 9;
    cnt[t] = 0;
    cnt[t + 256] = 0;
    __syncthreads();
    const int ebeg = bucketBase[b], eend = bucketBase[b + 1];
    for (int e = ebeg + t; e < eend; e += 256) {
        uint2 r = ebuf[e];
        atomicAdd(&cnt[r.y & 511], 1);
    }
    __syncthreads();
    int c0 = cnt[2 * t], c1 = cnt[2 * t + 1];
    int s = c0 + c1;
    red[t] = s;
    __syncthreads();
    for (int off = 1; off < 256; off <<= 1) {
        int v = (t >= off) ? red[t - off] : 0;
        __syncthreads();
        red[t] += v;
        __syncthreads();
    }
    int pre = red[t] - s;
    int n0 = node0 + 2 * t;
    if (n0 < N) rp[n0] = ebeg + pre;
    if (n0 + 1 < N) rp[n0 + 1] = ebeg + pre + c0;
    __syncthreads();
    cnt[2 * t] = ebeg + pre;
    cnt[2 * t + 1] = ebeg + pre + c0;
    __syncthreads();
    for (int e = ebeg + t; e < eend; e += 256) {
        uint2 r = ebuf[e];
        int p = atomicAdd(&cnt[r.y & 511], 1);
        csr[p] = (int)r.x;
    }
}

// ---------------- f32 -> bf16 conversion (x + all weights, one kernel) ----

struct WSeg { const float* s; us* d; int n4; int l2w4; int stride; };
struct WConvAll { WSeg seg[8]; };

__global__ void conv_all(WConvAll wc) {
    for (int sg = 0; sg < 8; ++sg) {
        WSeg w = wc.seg[sg];
        for (int i = blockIdx.x * blockDim.x + threadIdx.x; i < w.n4; i += gridDim.x * blockDim.x) {
            float4 v = ((const float4*)w.s)[i];
            ushort4 r;
            r.x = f2bf(v.x); r.y = f2bf(v.y); r.z = f2bf(v.z); r.w = f2bf(v.w);
            int row = i >> w.l2w4;
            int col = (i - (row << w.l2w4)) * 4;
            *(ushort4*)(w.d + (size_t)row * w.stride + col) = r;
        }
    }
}

// ---------------- mean aggregation (wave per node, unroll-4) ----------------

template <int VEC>  // cols = 64*VEC
__global__ void agg_mean(const us* __restrict__ X, const int* __restrict__ rp,
                         const int* __restrict__ csr, us* __restrict__ M, int n) {
    const int cols = VEC * 64;
    int w = blockIdx.x * (blockDim.x >> 6) + (threadIdx.x >> 6);
    int lane = threadIdx.x & 63;
    if (w >= n) return;
    int beg = rp[w], end = rp[w + 1];
    const us* Xb = X + lane * VEC;
    float acc[VEC];
#pragma unroll
    for (int i = 0; i < VEC; ++i) acc[i] = 0.f;
    int e = beg;
    for (; e + 4 <= end; e += 4) {
        int j0 = csr[e], j1 = csr[e + 1], j2 = csr[e + 2], j3 = csr[e + 3];
        if (VEC == 2) {
            unsigned u0 = *(const unsigned*)(Xb + (size_t)j0 * cols);
            unsigned u1 = *(const unsigned*)(Xb + (size_t)j1 * cols);
            unsigned u2 = *(const unsigned*)(Xb + (size_t)j2 * cols);
            unsigned u3 = *(const unsigned*)(Xb + (size_t)j3 * cols);
            acc[0] += __uint_as_float(u0 << 16) + __uint_as_float(u1 << 16)
                    + __uint_as_float(u2 << 16) + __uint_as_float(u3 << 16);
            acc[1] += __uint_as_float(u0 & 0xffff0000u) + __uint_as_float(u1 & 0xffff0000u)
                    + __uint_as_float(u2 & 0xffff0000u) + __uint_as_float(u3 & 0xffff0000u);
        } else {
            uint2 u0 = *(const uint2*)(Xb + (size_t)j0 * cols);
            uint2 u1 = *(const uint2*)(Xb + (size_t)j1 * cols);
            uint2 u2 = *(const uint2*)(Xb + (size_t)j2 * cols);
            uint2 u3 = *(const uint2*)(Xb + (size_t)j3 * cols);
            acc[0] += __uint_as_float(u0.x << 16) + __uint_as_float(u1.x << 16)
                    + __uint_as_float(u2.x << 16) + __uint_as_float(u3.x << 16);
            acc[1] += __uint_as_float(u0.x & 0xffff0000u) + __uint_as_float(u1.x & 0xffff0000u)
                    + __uint_as_float(u2.x & 0xffff0000u) + __uint_as_float(u3.x & 0xffff0000u);
            acc[2] += __uint_as_float(u0.y << 16) + __uint_as_float(u1.y << 16)
                    + __uint_as_float(u2.y << 16) + __uint_as_float(u3.y << 16);
            acc[3] += __uint_as_float(u0.y & 0xffff0000u) + __uint_as_float(u1.y & 0xffff0000u)
                    + __uint_as_float(u2.y & 0xffff0000u) + __uint_as_float(u3.y & 0xffff0000u);
        }
    }
    for (; e < end; ++e) {
        int j0 = csr[e];
        if (VEC == 2) {
            unsigned u0 = *(const unsigned*)(Xb + (size_t)j0 * cols);
            acc[0] += __uint_as_float(u0 << 16);
            acc[1] += __uint_as_float(u0 & 0xffff0000u);
        } else {
            uint2 u0 = *(const uint2*)(Xb + (size_t)j0 * cols);
            acc[0] += __uint_as_float(u0.x << 16);
            acc[1] += __uint_as_float(u0.x & 0xffff0000u);
            acc[2] += __uint_as_float(u0.y << 16);
            acc[3] += __uint_as_float(u0.y & 0xffff0000u);
        }
    }
    float inv = 1.0f / (float)max(end - beg, 1);
    us* q = M + (size_t)w * cols + lane * VEC;
    if (VEC == 2) {
        *(ushort2*)q = make_ushort2(f2bf(acc[0] * inv), f2bf(acc[1] * inv));
    } else {
        *(ushort4*)q = make_ushort4(f2bf(acc[0] * inv), f2bf(acc[1] * inv),
                                    f2bf(acc[2] * inv), f2bf(acc[3] * inv));
    }
}

// layer-3 post-GEMM aggregation (unroll-4)
__global__ void agg_post(const us* __restrict__ Yc, const int* __restrict__ rp,
                         const int* __restrict__ csr, const float* __restrict__ bias,
                         us* __restrict__ H, int n) {
    int w = blockIdx.x * (blockDim.x >> 6) + (threadIdx.x >> 6);
    int lane = threadIdx.x & 63;
    if (w >= n) return;
    int beg = rp[w], end = rp[w + 1];
    const us* Yb = Yc + lane * 2;
    float a0 = 0.f, a1 = 0.f;
    int e = beg;
    for (; e + 4 <= end; e += 4) {
        int j0 = csr[e], j1 = csr[e + 1], j2 = csr[e + 2], j3 = csr[e + 3];
        unsigned u0 = *(const unsigned*)(Yb + (size_t)j0 * 256);
        unsigned u1 = *(const unsigned*)(Yb + (size_t)j1 * 256);
        unsigned u2 = *(const unsigned*)(Yb + (size_t)j2 * 256);
        unsigned u3 = *(const unsigned*)(Yb + (size_t)j3 * 256);
        a0 += __uint_as_float(u0 << 16) + __uint_as_float(u1 << 16)
            + __uint_as_float(u2 << 16) + __uint_as_float(u3 << 16);
        a1 += __uint_as_float(u0 & 0xffff0000u) + __uint_as_float(u1 & 0xffff0000u)
            + __uint_as_float(u2 & 0xffff0000u) + __uint_as_float(u3 & 0xffff0000u);
    }
    for (; e < end; ++e) {
        unsigned u0 = *(const unsigned*)(Yb + (size_t)csr[e] * 256);
        a0 += __uint_as_float(u0 << 16);
        a1 += __uint_as_float(u0 & 0xffff0000u);
    }
    float inv = 1.0f / (float)max(end - beg, 1);
    unsigned uz = *(const unsigned*)(Yc + (size_t)w * 256 + 128 + lane * 2);
    float2 bv = *(const float2*)(bias + lane * 2);
    float r0 = a0 * inv + __uint_as_float(uz << 16) + bv.x;
    float r1 = a1 * inv + __uint_as_float(uz & 0xffff0000u) + bv.y;
    *(ushort2*)(H + (size_t)w * 128 + lane * 2) = make_ushort2(f2bf(r0), f2bf(r1));
}

// ---------------- MFMA GEMM: distance-2 DMA pipeline, dual LDS buffers ----
// C = [A0|A1] @ W^T + bias; optional replicated BN-stats accumulation.
// THREADS/64 waves of WM x WN tile a BM x BN block.

template <int THREADS, int BM, int BN, int WM, int WN>
__launch_bounds__(THREADS)
__global__ void gemm_mfma(const us* __restrict__ A0, int K0,
                          const us* __restrict__ A1, int K1,
                          const us* __restrict__ W, const float* __restrict__ bias,
                          int n, int outc, us* __restrict__ Cbf, float* __restrict__ Cf,
                          float* __restrict__ st0, float* __restrict__ st1) {
    constexpr int MT = WM / 16;
    constexpr int NT = WN / 16;
    constexpr int WCols = BN / WN;
    constexpr int NDMA = (BM * 4 + BN * 4) / THREADS;  // DMA instrs per wave/tile
    static_assert((BM * 4) % THREADS == 0 && (BN * 4) % THREADS == 0, "uniform DMA");
    static_assert((BM / WM) * (BN / WN) == THREADS / 64, "wave tiling");
    __shared__ __align__(16) us As[2][BM * 32];
    __shared__ __align__(16) us Bs[2][BN * 32];
    __shared__ float colred[2][BN];

    const int t = threadIdx.x;
    const int wid = t >> 6, lane = t & 63;
    const int wr = wid / WCols, wcc = wid % WCols;
    const int row0 = blockIdx.x * BM;
    const int col0 = blockIdx.y * BN;
    const int Kp = K0 + K1;
    const int nk = Kp >> 5;
    const int l15 = lane & 15, l4 = lane >> 4;

    auto issue = [&](int kidx, int p) {
        int kc = kidx << 5;
        const us* A = (kc < K0) ? A0 : A1;
        int rs = (kc < K0) ? K0 : K1;
        int ko = (kc < K0) ? kc : kc - K0;
#pragma unroll
        for (int c = t; c < BM * 4; c += THREADS) {
            int blk = c >> 6;
            int row = row0 + (blk << 4) + l15;
            gll16(A + (size_t)row * rs + ko + (l4 << 3), (char*)As[p] + blk * 1024 + lane * 16);
        }
#pragma unroll
        for (int c = t; c < BN * 4; c += THREADS) {
            int blk = c >> 6;
            int col = col0 + (blk << 4) + l15;
            gll16(W + (size_t)col * Kp + kc + (l4 << 3), (char*)Bs[p] + blk * 1024 + lane * 16);
        }
    };

    f32x4 acc[MT][NT];
#pragma unroll
    for (int i = 0; i < MT; ++i)
#pragma unroll
        for (int j = 0; j < NT; ++j) acc[i][j] = (f32x4){0.f, 0.f, 0.f, 0.f};

    issue(0, 0);
    if (nk > 1) issue(1, 1);
    for (int k = 0; k < nk; ++k) {
        // retire tile k's DMAs only; tile k+1 stays in flight
        if (k + 1 < nk) asm volatile("s_waitcnt vmcnt(%0)" :: "i"(NDMA) : "memory");
        else            asm volatile("s_waitcnt vmcnt(0)" ::: "memory");
        asm volatile("s_barrier" ::: "memory");
        const int p = k & 1;
        bf16x8 af[MT], bfr[NT];
#pragma unroll
        for (int mt = 0; mt < MT; ++mt)
            af[mt] = *(const bf16x8*)((char*)As[p] + (wr * MT + mt) * 1024 + lane * 16);
#pragma unroll
        for (int nt = 0; nt < NT; ++nt)
            bfr[nt] = *(const bf16x8*)((char*)Bs[p] + (wcc * NT + nt) * 1024 + lane * 16);
#pragma unroll
        for (int mt = 0; mt < MT; ++mt)
#pragma unroll
            for (int nt = 0; nt < NT; ++nt)
                acc[mt][nt] = __builtin_amdgcn_mfma_f32_16x16x32_bf16(af[mt], bfr[nt], acc[mt][nt], 0, 0, 0);
        if (k + 2 < nk) {
            asm volatile("s_barrier" ::: "memory");  // all waves done reading buf p
            issue(k + 2, p);
        }
    }

    if (st0) {
#pragma unroll
        for (int c = t; c < 2 * BN; c += THREADS) (&colred[0][0])[c] = 0.f;
        __syncthreads();
    }

    // epilogue: C/D map col=lane&15, row=(lane>>4)*4+reg
#pragma unroll
    for (int nt = 0; nt < NT; ++nt) {
        int col = col0 + wcc * WN + nt * 16 + l15;
        bool cok = col < outc;
        float bv = (bias != nullptr && cok) ? bias[col] : 0.f;
        float ls = 0.f, lq = 0.f;
#pragma unroll
        for (int mt = 0; mt < MT; ++mt) {
            int rbase = row0 + wr * WM + mt * 16 + (l4 << 2);
#pragma unroll
            for (int i = 0; i < 4; ++i) {
                int r = rbase + i;
                if (r < n && cok) {
                    float v = acc[mt][nt][i] + bv;
                    if (Cf) Cf[(size_t)r * outc + col] = v;
                    else Cbf[(size_t)r * outc + col] = f2bf(v);
                    ls += v;
                    lq += v * v;
                }
            }
        }
        if (st0 && cok) {
            int lc = wcc * WN + nt * 16 + l15;
            atomicAdd(&colred[0][lc], ls);
            atomicAdd(&colred[1][lc], lq);
        }
    }
    if (st0) {
        __syncthreads();
        int rep = (blockIdx.x & 7) << 8;  // 8-way replicated accumulators
        for (int c = t; c < BN; c += THREADS) {
            if (col0 + c < outc) {
                atomicAdd(&st0[rep + col0 + c], colred[0][c]);
                atomicAdd(&st1[rep + col0 + c], colred[1][c]);
            }
        }
    }
}

// ---------------- BatchNorm ----------------

__global__ void bn_stats(const us* __restrict__ H, int n, int c,
                         float* __restrict__ s0, float* __restrict__ s1) {
    int col = threadIdx.x;
    if (col >= c) return;
    float s = 0.f, q = 0.f;
    for (int r = blockIdx.x; r < n; r += gridDim.x) {
        float v = bf2f(H[(size_t)r * c + col]);
        s += v;
        q += v * v;
    }
    int rep = (blockIdx.x & 7) << 8;
    atomicAdd(&s0[rep + col], s);
    atomicAdd(&s1[rep + col], q);
}

// bn_apply with inline finalize (sums 8 stat replicas).
__global__ void bn_apply(us* __restrict__ H, int n8, int c,
                         const float* __restrict__ s0, const float* __restrict__ s1,
                         const float* __restrict__ g, const float* __restrict__ be, float fn) {
    __shared__ float sc[256], sh[256];
    int t = threadIdx.x;
    if (t < c) {
        float s = 0.f, q = 0.f;
#pragma unroll
        for (int r = 0; r < 8; ++r) {
            s += s0[(r << 8) + t];
            q += s1[(r << 8) + t];
        }
        float mean = s / fn;
        float var = q / fn - mean * mean;
        float scale = g[t] * rsqrtf(var + 1e-5f);
        sc[t] = scale;
        sh[t] = be[t] - mean * scale;
    }
    __syncthreads();
    int cdiv8 = c >> 3;
    for (int i = blockIdx.x * blockDim.x + t; i < n8; i += gridDim.x * blockDim.x) {
        int col = (i % cdiv8) << 3;
        uint4 v = ((const uint4*)H)[i];
        float f[8];
        f[0] = __uint_as_float(v.x << 16); f[1] = __uint_as_float(v.x & 0xffff0000u);
        f[2] = __uint_as_float(v.y << 16); f[3] = __uint_as_float(v.y & 0xffff0000u);
        f[4] = __uint_as_float(v.z << 16); f[5] = __uint_as_float(v.z & 0xffff0000u);
        f[6] = __uint_as_float(v.w << 16); f[7] = __uint_as_float(v.w & 0xffff0000u);
        float4 sc0 = *(const float4*)&sc[col];
        float4 sc1 = *(const float4*)&sc[col + 4];
        float4 sh0 = *(const float4*)&sh[col];
        float4 sh1 = *(const float4*)&sh[col + 4];
        f[0] = fmaxf(f[0] * sc0.x + sh0.x, 0.f);
        f[1] = fmaxf(f[1] * sc0.y + sh0.y, 0.f);
        f[2] = fmaxf(f[2] * sc0.z + sh0.z, 0.f);
        f[3] = fmaxf(f[3] * sc0.w + sh0.w, 0.f);
        f[4] = fmaxf(f[4] * sc1.x + sh1.x, 0.f);
        f[5] = fmaxf(f[5] * sc1.y + sh1.y, 0.f);
        f[6] = fmaxf(f[6] * sc1.z + sh1.z, 0.f);
        f[7] = fmaxf(f[7] * sc1.w + sh1.w, 0.f);
        uint4 o;
        o.x = (unsigned)f2bf(f[0]) | ((unsigned)f2bf(f[1]) << 16);
        o.y = (unsigned)f2bf(f[2]) | ((unsigned)f2bf(f[3]) << 16);
        o.z = (unsigned)f2bf(f[4]) | ((unsigned)f2bf(f[5]) << 16);
        o.w = (unsigned)f2bf(f[6]) | ((unsigned)f2bf(f[7]) << 16);
        ((uint4*)H)[i] = o;
    }
}

// ---------------- host ----------------

extern "C" void kernel_launch(void* const* d_in, const int* in_sizes, int n_in,
                              void* d_out, int out_size, void* d_ws, size_t ws_size,
                              hipStream_t stream) {
    const float* x = (const float*)d_in[0];
    const int* ei = (const int*)d_in[1];
    const float* w1_l = (const float*)d_in[2];
    const float* b1_l = (const float*)d_in[3];
    const float* w1_r = (const float*)d_in[4];
    const float* g1 = (const float*)d_in[5];
    const float* be1 = (const float*)d_in[6];
    const float* w2_l = (const float*)d_in[7];
    const float* b2_l = (const float*)d_in[8];
    const float* w2_r = (const float*)d_in[9];
    const float* g2 = (const float*)d_in[10];
    const float* be2 = (const float*)d_in[11];
    const float* w3_l = (const float*)d_in[12];
    const float* b3_l = (const float*)d_in[13];
    const float* w3_r = (const float*)d_in[14];
    const float* g3 = (const float*)d_in[15];
    const float* be3 = (const float*)d_in[16];
    const float* wcf = (const float*)d_in[17];
    const float* bc = (const float*)d_in[18];

    const int N = in_sizes[0] / 128;
    const int E = in_sizes[1] / 2;
    const int NB = (N + 511) >> 9;
    const int G = 256;
    const int chunk = (E + G - 1) / G;

    char* ws = (char*)d_ws;
    size_t off = 0;
    auto alloc = [&](size_t bytes) -> char* {
        char* p = ws + off;
        off += (bytes + 255) & ~(size_t)255;
        return p;
    };
    int* rp = (int*)alloc((size_t)(N + 1) * 4);
    int* csr = (int*)alloc((size_t)E * 4);
    int* hist2 = (int*)alloc((size_t)G * NB * 4);
    int* bucketBase = (int*)alloc((size_t)(NB + 1) * 4);
    uint2* ebuf = (uint2*)alloc((size_t)E * 8);
    us* xbf = (us*)alloc((size_t)N * 128 * 2);
    us* M = (us*)alloc((size_t)N * 256 * 2);   // gather out / Yc
    us* Ha = (us*)alloc((size_t)N * 256 * 2);  // h1; later h3
    us* Hb = (us*)alloc((size_t)N * 256 * 2);  // h2
    float* stats = (float*)alloc(6 * 8 * 256 * 4);
    float* s01 = stats,          *s11 = stats + 2048;
    float* s02 = stats + 4096,   *s12 = stats + 6144;
    float* s03 = stats + 8192,   *s13 = stats + 10240;
    us* wcat1 = (us*)alloc(256 * 256 * 2);     // [256][128+128] = [w1_l | w1_r]
    us* wcat2 = (us*)alloc(256 * 512 * 2);     // [256][256+256] = [w2_l | w2_r]
    us* w3cat = (us*)alloc(256 * 256 * 2);     // rows 0-127 w3_l, 128-255 w3_r
    us* wc_b = (us*)alloc(64 * 128 * 2);       // 64 rows (rows 15-63 masked)
    alloc(1 << 20);                             // pad: absorbs OOB staging reads
    (void)ws_size; (void)n_in; (void)out_size;

    // --- conversions + CSR build + stat zero ---
    hipMemsetAsync(stats, 0, 6 * 8 * 256 * 4, stream);
    WConvAll wc;
    wc.seg[0] = {x,    xbf,         N * 128 / 4,  5, 128};
    wc.seg[1] = {w1_l, wcat1,       256 * 128 / 4, 5, 256};
    wc.seg[2] = {w1_r, wcat1 + 128, 256 * 128 / 4, 5, 256};
    wc.seg[3] = {w2_l, wcat2,       256 * 256 / 4, 6, 512};
    wc.seg[4] = {w2_r, wcat2 + 256, 256 * 256 / 4, 6, 512};
    wc.seg[5] = {w3_l, w3cat,             128 * 256 / 4, 6, 256};
    wc.seg[6] = {w3_r, w3cat + 128 * 256, 128 * 256 / 4, 6, 256};
    wc.seg[7] = {wcf,  wc_b,        15 * 128 / 4,  5, 128};
    conv_all<<<1024, 256, 0, stream>>>(wc);
    bucket_hist<<<G, 256, 0, stream>>>(ei, E, hist2, NB, chunk);
    bucket_offsets<<<1, 256, 0, stream>>>(hist2, bucketBase, rp, N, G, NB);
    scatter8<<<G, 256, 0, stream>>>(ei, E, hist2, ebuf, NB, chunk);
    fine_csr<<<NB, 256, 0, stream>>>(ebuf, bucketBase, N, rp, csr);

    const int aggGrid = (N + 3) / 4;
    const int rowTiles = (N + 127) / 128;

    // --- layer 1: 128 -> 256 (stats fused) ---
    agg_mean<2><<<aggGrid, 256, 0, stream>>>(xbf, rp, csr, M, N);
    gemm_mfma<512, 128, 256, 64, 64><<<rowTiles, 512, 0, stream>>>(
        M, 128, xbf, 128, wcat1, b1_l, N, 256, Ha, nullptr, s01, s11);
    bn_apply<<<2048, 256, 0, stream>>>(Ha, N * 256 / 8, 256, s01, s11, g1, be1, (float)N);

    // --- layer 2: 256 -> 256 (stats fused) ---
    agg_mean<4><<<aggGrid, 256, 0, stream>>>(Ha, rp, csr, M, N);
    gemm_mfma<512, 128, 256, 64, 64><<<rowTiles, 512, 0, stream>>>(
        M, 256, Ha, 256, wcat2, b2_l, N, 256, Hb, nullptr, s02, s12);
    bn_apply<<<2048, 256, 0, stream>>>(Hb, N * 256 / 8, 256, s02, s12, g2, be2, (float)N);

    // --- layer 3: GEMM-first: [Y|Z] = Hb @ [w3l;w3r]^T, aggregate 128 cols ---
    gemm_mfma<512, 128, 256, 64, 64><<<rowTiles, 512, 0, stream>>>(
        Hb, 256, nullptr, 0, w3cat, nullptr, N, 256, M, nullptr, nullptr, nullptr);
    agg_post<<<aggGrid, 256, 0, stream>>>(M, rp, csr, b3_l, Ha, N);
    bn_stats<<<1024, 256, 0, stream>>>(Ha, N, 128, s03, s13);
    bn_apply<<<2048, 256, 0, stream>>>(Ha, N * 128 / 8, 128, s03, s13, g3, be3, (float)N);

    // --- classifier: 128 -> 15 (f32 out) ---
    gemm_mfma<256, 128, 64, 128, 16><<<rowTiles, 256, 0, stream>>>(
        Ha, 128, nullptr, 0, wc_b, bc, N, 15, nullptr, (float*)d_out, nullptr, nullptr);
}